// Round 3
// baseline (1041.566 us; speedup 1.0000x reference)
//
#include <hip/hip_runtime.h>
#include <hip/hip_bf16.h>
#include <math.h>

#define HH 240
#define WW 1216
#define BATCH 4
#define PROP 6
constexpr int HW = HH * WW;            // 291,840
constexpr int NPIX = BATCH * HW;       // 1,167,360
constexpr int NPART = 1024;

// ---------------------------------------------------------------------------
// Propagation v3: P=4 pixels per lane to amortize weight fetches.
// Tile 256x4 px. Guidance ext tile + all 1800 weights staged in LDS.
// Inner loop: 1 broadcast weight read feeds 4 FMAs.
// ---------------------------------------------------------------------------
__global__ __launch_bounds__(256, 2) void prop_kernel(
    const float* __restrict__ featPrev,   // [B][HW]
    const float* __restrict__ gbase,      // guidance + 8k*HW; batch stride 48*HW
    const float* __restrict__ aw,         // [9][8][3][3]
    const float* __restrict__ ab,         // [9]
    const float* __restrict__ ow,         // [16][8][3][3]
    const float* __restrict__ ob,         // [16]
    const float* __restrict__ w3,         // [9]
    const float* __restrict__ b3,         // [1]
    float* __restrict__ featNext)         // [B][HW]
{
    __shared__ float gs[8][6][260];       // guidance ext tile, rows y0-1..y0+4
    __shared__ float wl[8][25][12];       // weights [ch][out][tap(padded)]

    const int tid = threadIdx.x;
    const int x0 = blockIdx.x * 256;
    const int y0t = blockIdx.y * 4;
    const int b = blockIdx.z;
    const float* gb = gbase + (size_t)b * (48 * HW);

    // ---- stage weights: wl[c][o][t] ----
    for (int idx = tid; idx < 1800; idx += 256) {
        const int c = idx / 225, rem = idx - c * 225;
        const int o = rem / 9, t = rem - o * 9;
        wl[c][o][t] = (o < 9) ? aw[(o * 8 + c) * 9 + t]
                              : ow[((o - 9) * 8 + c) * 9 + t];
    }
    // ---- stage guidance ext tile (zero-pad = conv zero-pad) ----
    for (int idx = tid; idx < 8 * 6 * 258; idx += 256) {
        const int c = idx / (6 * 258), rem = idx - c * (6 * 258);
        const int r = rem / 258, col = rem - r * 258;
        const int gy = y0t + r - 1, gx = x0 + col - 1;
        float v = 0.0f;
        if (((unsigned)gy < (unsigned)HH) & ((unsigned)gx < (unsigned)WW))
            v = gb[c * HW + gy * WW + gx];
        gs[c][r][col] = v;
    }
    __syncthreads();

    const int lane = tid & 63;
    const int wrow = tid >> 6;            // 0..3
    const int y = y0t + wrow;
    const int xb = x0 + 4 * lane;         // first of this lane's 4 px

    float acc[4][25];
#pragma unroll
    for (int o = 0; o < 9; ++o) {
        const float bv = ab[o];
#pragma unroll
        for (int j = 0; j < 4; ++j) acc[j][o] = bv;
    }
#pragma unroll
    for (int o = 0; o < 16; ++o) {
        const float bv = ob[o];
#pragma unroll
        for (int j = 0; j < 4; ++j) acc[j][9 + o] = bv;
    }

#pragma unroll 1
    for (int c = 0; c < 8; ++c) {
        // 3 rows x 6 cols window for this lane's 4 px (16B-aligned starts)
        float g6[3][6];
#pragma unroll
        for (int r = 0; r < 3; ++r) {
            const float4 a4 = *(const float4*)&gs[c][wrow + r][4 * lane];
            const float2 a2 = *(const float2*)&gs[c][wrow + r][4 * lane + 4];
            g6[r][0] = a4.x; g6[r][1] = a4.y; g6[r][2] = a4.z;
            g6[r][3] = a4.w; g6[r][4] = a2.x; g6[r][5] = a2.y;
        }
#pragma unroll
        for (int o = 0; o < 25; ++o) {
            const float4 w0 = *(const float4*)&wl[c][o][0];
            const float4 w1 = *(const float4*)&wl[c][o][4];
            const float w8 = wl[c][o][8];
            const float wv[9] = {w0.x, w0.y, w0.z, w0.w, w1.x, w1.y, w1.z, w1.w, w8};
#pragma unroll
            for (int t = 0; t < 9; ++t) {
                const int r = t / 3, dc = t % 3;
#pragma unroll
                for (int j = 0; j < 4; ++j)
                    acc[j][o] = fmaf(g6[r][j + dc], wv[t], acc[j][o]);
            }
        }
    }

    if (xb >= WW) return;   // partial tail tile: whole lane OOB (192 = 4*48)

    const float* fb = featPrev + (size_t)b * HW;
    float res[4];

#pragma unroll
    for (int j = 0; j < 4; ++j) {
        const int x = xb + j;
        // sigmoid + sum
        float wg[9];
        float wsum = 1e-8f;
#pragma unroll
        for (int t = 0; t < 9; ++t) {
            const float s = 1.0f / (1.0f + __expf(-acc[j][t]));
            wg[t] = s;
            wsum += s;
        }
        const float winv = 1.0f / wsum;

        float sum = 0.0f;
#pragma unroll
        for (int t = 0; t < 9; ++t) {
            float oy, ox;
            if (t < 4)       { oy = acc[j][9 + 2 * t]; ox = acc[j][10 + 2 * t]; }
            else if (t == 4) { oy = 0.0f;              ox = 0.0f; }
            else             { oy = acc[j][7 + 2 * t]; ox = acc[j][8 + 2 * t]; }

            const float py = (float)(y - 1 + (t / 3)) + oy;
            const float px = (float)(x - 1 + (t % 3)) + ox;
            const float fy = floorf(py), fx = floorf(px);
            const float wy = py - fy, wx = px - fx;
            const int iy = (int)fy, ix = (int)fx;
            const int iy1 = iy + 1, ix1 = ix + 1;

            const int ry0 = min(max(iy, 0), HH - 1) * WW;
            const int ry1 = min(max(iy1, 0), HH - 1) * WW;
            const int cx0 = min(max(ix, 0), WW - 1);
            const int cx1 = min(max(ix1, 0), WW - 1);
            const float v00 = fb[ry0 + cx0], v01 = fb[ry0 + cx1];
            const float v10 = fb[ry1 + cx0], v11 = fb[ry1 + cx1];

            const bool vy0 = (unsigned)iy < (unsigned)HH;
            const bool vy1 = (unsigned)iy1 < (unsigned)HH;
            const bool vx0 = (unsigned)ix < (unsigned)WW;
            const bool vx1 = (unsigned)ix1 < (unsigned)WW;
            const float wy0 = 1.0f - wy, wx0 = 1.0f - wx;

            float s = 0.0f;
            s = fmaf((vy0 & vx0) ? wy0 * wx0 : 0.0f, v00, s);
            s = fmaf((vy0 & vx1) ? wy0 * wx  : 0.0f, v01, s);
            s = fmaf((vy1 & vx0) ? wy  * wx0 : 0.0f, v10, s);
            s = fmaf((vy1 & vx1) ? wy  * wx  : 0.0f, v11, s);

            sum = fmaf(wg[t] * w3[t], s, sum);
        }
        res[j] = fmaf(winv, sum, b3[0]);
    }

    float4 r4;
    r4.x = res[0]; r4.y = res[1]; r4.z = res[2]; r4.w = res[3];
    *(float4*)&featNext[(size_t)b * HW + (size_t)y * WW + xb] = r4;
}

// ---------------------------------------------------------------------------
// Stage 1 of BN stats: per-block partial sums of y0,y1,y2 and their products.
// ---------------------------------------------------------------------------
__global__ __launch_bounds__(256) void stats_part(
    const float* __restrict__ y0s, const float* __restrict__ y1s,
    const float* __restrict__ y2s, float* __restrict__ part)
{
    float a[9] = {0, 0, 0, 0, 0, 0, 0, 0, 0};
    const int stride = gridDim.x * 256;
    for (int i = blockIdx.x * 256 + threadIdx.x; i < NPIX; i += stride) {
        const float v0 = y0s[i], v1 = y1s[i], v2 = y2s[i];
        a[0] += v0; a[1] += v1; a[2] += v2;
        a[3] = fmaf(v0, v0, a[3]); a[4] = fmaf(v0, v1, a[4]);
        a[5] = fmaf(v0, v2, a[5]); a[6] = fmaf(v1, v1, a[6]);
        a[7] = fmaf(v1, v2, a[7]); a[8] = fmaf(v2, v2, a[8]);
    }
    __shared__ float red[4][9];
    const int lane = threadIdx.x & 63, wv = threadIdx.x >> 6;
#pragma unroll
    for (int q = 0; q < 9; ++q) {
        float v = a[q];
        for (int o = 32; o; o >>= 1) v += __shfl_down(v, o, 64);
        if (lane == 0) red[wv][q] = v;
    }
    __syncthreads();
    if (threadIdx.x < 9) {
        const int q = threadIdx.x;
        part[blockIdx.x * 9 + q] = red[0][q] + red[1][q] + red[2][q] + red[3][q];
    }
}

// ---------------------------------------------------------------------------
// Stage 2: finalize per-channel BN scale/shift for sf = proj(y).
// ---------------------------------------------------------------------------
__global__ __launch_bounds__(256) void stats_final(
    const float* __restrict__ part, const float* __restrict__ proj_w,
    const float* __restrict__ bn_g, const float* __restrict__ bn_b,
    float* __restrict__ stats)
{
    float a[9] = {0, 0, 0, 0, 0, 0, 0, 0, 0};
    for (int i = threadIdx.x; i < NPART; i += 256) {
#pragma unroll
        for (int q = 0; q < 9; ++q) a[q] += part[i * 9 + q];
    }
    __shared__ float red[4][9];
    const int lane = threadIdx.x & 63, wv = threadIdx.x >> 6;
#pragma unroll
    for (int q = 0; q < 9; ++q) {
        float v = a[q];
        for (int o = 32; o; o >>= 1) v += __shfl_down(v, o, 64);
        if (lane == 0) red[wv][q] = v;
    }
    __syncthreads();
    if (threadIdx.x == 0) {
        float s[9];
#pragma unroll
        for (int q = 0; q < 9; ++q) s[q] = red[0][q] + red[1][q] + red[2][q] + red[3][q];
        const float invN = 1.0f / (float)NPIX;
        const float m0 = s[0] * invN, m1 = s[1] * invN, m2 = s[2] * invN;
        const float E00 = s[3] * invN, E01 = s[4] * invN, E02 = s[5] * invN;
        const float E11 = s[6] * invN, E12 = s[7] * invN, E22 = s[8] * invN;
#pragma unroll
        for (int c = 0; c < 6; ++c) {
            const float p0 = proj_w[c * 3], p1 = proj_w[c * 3 + 1], p2 = proj_w[c * 3 + 2];
            const float mu = p0 * m0 + p1 * m1 + p2 * m2;
            const float e2 = p0 * p0 * E00 + p1 * p1 * E11 + p2 * p2 * E22 +
                             2.0f * (p0 * p1 * E01 + p0 * p2 * E02 + p1 * p2 * E12);
            const float var = e2 - mu * mu;
            const float sc = bn_g[c] / sqrtf(var + 1e-5f);
            stats[c] = sc;
            stats[6 + c] = bn_b[c] - mu * sc;
        }
    }
}

// ---------------------------------------------------------------------------
// Fused head, tile 32x8. a1/a2 carried in registers (no LDS round-trip);
// 84 extra ring jobs fill the agg halo.
// ---------------------------------------------------------------------------
__global__ __launch_bounds__(256, 4) void head_kernel(
    const float* __restrict__ y0s, const float* __restrict__ y1s,
    const float* __restrict__ y2s, const float* __restrict__ attn,
    const float* __restrict__ stats,   // scale[6], shift[6]
    const float* __restrict__ proj_w,
    const float* __restrict__ c0_w, const float* __restrict__ c0_b,
    const float* __restrict__ cs_w, const float* __restrict__ cs_b,
    const float* __restrict__ c1_w, const float* __restrict__ c1_b,
    const float* __restrict__ c2_w, const float* __restrict__ c2_b,
    const float* __restrict__ csq_w, const float* __restrict__ csq_b,
    const float* __restrict__ cv_w, const float* __restrict__ cv_b,
    float* __restrict__ out)
{
    __shared__ float ap[22][432];    // a1_pre, ext tile 12x36 (halo 2)
    __shared__ float aggs[2][340];   // agg, tile+halo1 10x34

    const int tid = threadIdx.x;
    const int b = blockIdx.z;
    const int x0 = blockIdx.x * 32;
    const int y0t = blockIdx.y * 8;

    // ---- phase 1: a1_pre over ext tile (zero outside image = conv pad) ----
    for (int idx = tid; idx < 432; idx += 256) {
        const int eyl = idx / 36, exl = idx - eyl * 36;
        const int gy = y0t + eyl - 2, gx = x0 + exl - 2;
        float v[22];
        if (((unsigned)gy < (unsigned)HH) & ((unsigned)gx < (unsigned)WW)) {
            const size_t p = (size_t)gy * WW + gx;
            const float* abp = attn + (size_t)b * 16 * HW + p;
#pragma unroll
            for (int c = 0; c < 16; ++c)
                v[c] = fmaf(c0_w[c], abp[(size_t)c * HW], c0_b[c]);
            const float ym0 = y0s[(size_t)b * HW + p];
            const float ym1 = y1s[(size_t)b * HW + p];
            const float ym2 = y2s[(size_t)b * HW + p];
#pragma unroll
            for (int j = 0; j < 6; ++j) {
                const float sraw = proj_w[j * 3] * ym0 + proj_w[j * 3 + 1] * ym1 +
                                   proj_w[j * 3 + 2] * ym2;
                float sf = fmaf(stats[j], sraw, stats[6 + j]);
                sf = sf > 0.0f ? sf : 0.2f * sf;
                v[16 + j] = fmaf(c0_w[16 + j], sf, c0_b[16 + j]);
            }
        } else {
#pragma unroll
            for (int c = 0; c < 22; ++c) v[c] = 0.0f;
        }
#pragma unroll
        for (int c = 0; c < 22; ++c) ap[c][idx] = v[c];
    }
    __syncthreads();

    // computes a1[11], a2[11] at agg coords (ay,ax)
    auto compute_px = [&](int ay, int ax, float* a1, float* a2) {
        const int ey = ay + 1, ex = ax + 1;   // ext coords
#pragma unroll
        for (int j = 0; j < 11; ++j) { a1[j] = c1_b[j]; a2[j] = c2_b[j]; }
#pragma unroll
        for (int c = 0; c < 22; ++c) {
            float dw = cs_b[c];
            float ctr = 0.0f;
#pragma unroll
            for (int t = 0; t < 9; ++t) {
                const float av = ap[c][(ey + t / 3 - 1) * 36 + (ex + t % 3 - 1)];
                dw = fmaf(cs_w[c * 9 + t], av, dw);
                if (t == 4) ctr = av;
            }
#pragma unroll
            for (int j = 0; j < 11; ++j) {
                a1[j] = fmaf(c1_w[j * 22 + c], ctr, a1[j]);
                a2[j] = fmaf(c2_w[j * 22 + c], dw, a2[j]);
            }
        }
    };

    // ---- phase 2a: ring jobs (84 halo pixels of the 10x34 agg region) ----
    if (tid < 84) {
        int ay, ax;
        if (tid < 34)      { ay = 0; ax = tid; }
        else if (tid < 68) { ay = 9; ax = tid - 34; }
        else { const int s = tid - 68; ay = 1 + (s >> 1); ax = (s & 1) ? 33 : 0; }
        const int gy = y0t + ay - 1, gx = x0 + ax - 1;
        float m0 = 0.0f, m1 = 0.0f;
        if (((unsigned)gy < (unsigned)HH) & ((unsigned)gx < (unsigned)WW)) {
            float a1h[11], a2h[11];
            compute_px(ay, ax, a1h, a2h);
            float s = 0.0f, mx = -INFINITY;
#pragma unroll
            for (int j = 0; j < 11; ++j) {
                s += a1h[j] + a2h[j];
                mx = fmaxf(mx, fmaxf(a1h[j], a2h[j]));
            }
            m0 = s * (1.0f / 22.0f);
            m1 = mx;
        }
        aggs[0][ay * 34 + ax] = m0;
        aggs[1][ay * 34 + ax] = m1;
    }

    // ---- phase 2b: center pixel, keep a1/a2 in registers ----
    const int ty = tid >> 5, tx = tid & 31;
    const int ay = ty + 1, ax = tx + 1;
    float a1[11], a2[11];
    compute_px(ay, ax, a1, a2);
    {
        float s = 0.0f, mx = -INFINITY;
#pragma unroll
        for (int j = 0; j < 11; ++j) {
            s += a1[j] + a2[j];
            mx = fmaxf(mx, fmaxf(a1[j], a2[j]));
        }
        aggs[0][ay * 34 + ax] = s * (1.0f / 22.0f);
        aggs[1][ay * 34 + ax] = mx;
    }
    __syncthreads();

    // ---- phase 3: sigmoid gate + cv + final dot with y ----
    float z0 = csq_b[0], z1 = csq_b[1];
#pragma unroll
    for (int t = 0; t < 9; ++t) {
        const int ai = (ay + t / 3 - 1) * 34 + (ax + t % 3 - 1);
        const float g0 = aggs[0][ai], g1 = aggs[1][ai];
        z0 = fmaf(csq_w[t], g0, fmaf(csq_w[9 + t], g1, z0));
        z1 = fmaf(csq_w[18 + t], g0, fmaf(csq_w[27 + t], g1, z1));
    }
    const float s0 = 1.0f / (1.0f + __expf(-z0));
    const float s1 = 1.0f / (1.0f + __expf(-z1));
    float v0 = cv_b[0], v1 = cv_b[1], v2 = cv_b[2];
#pragma unroll
    for (int j = 0; j < 11; ++j) {
        const float av = a1[j] * s0 + a2[j] * s1;
        v0 = fmaf(cv_w[j], av, v0);
        v1 = fmaf(cv_w[11 + j], av, v1);
        v2 = fmaf(cv_w[22 + j], av, v2);
    }
    const size_t p = (size_t)b * HW + (size_t)(y0t + ty) * WW + (x0 + tx);
    out[p] = y0s[p] * v0 + y1s[p] * v1 + y2s[p] * v2;
}

// ---------------------------------------------------------------------------
extern "C" void kernel_launch(void* const* d_in, const int* in_sizes, int n_in,
                              void* d_out, int out_size, void* d_ws, size_t ws_size,
                              hipStream_t stream)
{
    (void)in_sizes; (void)n_in; (void)out_size; (void)ws_size;
    const float* feat_init = (const float*)d_in[0];
    const float* guidance  = (const float*)d_in[1];
    const float* attn      = (const float*)d_in[2];
    const float* aff_w_w   = (const float*)d_in[4];
    const float* aff_w_b   = (const float*)d_in[5];
    const float* aff_o_w   = (const float*)d_in[6];
    const float* aff_o_b   = (const float*)d_in[7];
    const float* w3        = (const float*)d_in[8];
    const float* b3        = (const float*)d_in[9];
    const float* proj_w    = (const float*)d_in[10];
    const float* bn_g      = (const float*)d_in[11];
    const float* bn_b      = (const float*)d_in[12];
    const float* c0_w      = (const float*)d_in[13];
    const float* c0_b      = (const float*)d_in[14];
    const float* cs_w      = (const float*)d_in[15];
    const float* cs_b      = (const float*)d_in[16];
    const float* c1_w      = (const float*)d_in[17];
    const float* c1_b      = (const float*)d_in[18];
    const float* c2_w      = (const float*)d_in[19];
    const float* c2_b      = (const float*)d_in[20];
    const float* csq_w     = (const float*)d_in[21];
    const float* csq_b     = (const float*)d_in[22];
    const float* cv_w      = (const float*)d_in[23];
    const float* cv_b      = (const float*)d_in[24];

    float* ws = (float*)d_ws;
    float* slot[5];
    for (int i = 0; i < 5; ++i) slot[i] = ws + (size_t)i * NPIX;
    float* part  = ws + (size_t)5 * NPIX;
    float* stats = part + (size_t)9 * NPART;

    const dim3 blk(256);
    const dim3 gp((WW + 255) / 256, HH / 4, BATCH);

    // propagation chain; keep feats[3],[4],[5] in slots 2,3,4
    const int dst_ids[PROP] = {0, 1, 0, 2, 3, 4};
    const float* src = feat_init;
    for (int k = 0; k < PROP; ++k) {
        float* dst = slot[dst_ids[k]];
        prop_kernel<<<gp, blk, 0, stream>>>(
            src, guidance + (size_t)8 * k * HW,
            aff_w_w + (size_t)k * 648, aff_w_b + (size_t)k * 9,
            aff_o_w + (size_t)k * 1152, aff_o_b + (size_t)k * 16,
            w3, b3, dst);
        src = dst;
    }

    stats_part<<<dim3(NPART), blk, 0, stream>>>(slot[2], slot[3], slot[4], part);
    stats_final<<<dim3(1), blk, 0, stream>>>(part, proj_w, bn_g, bn_b, stats);

    head_kernel<<<dim3(WW / 32, HH / 8, BATCH), blk, 0, stream>>>(
        slot[2], slot[3], slot[4], attn, stats, proj_w,
        c0_w, c0_b, cs_w, cs_b, c1_w, c1_b, c2_w, c2_b,
        csq_w, csq_b, cv_w, cv_b, (float*)d_out);
}

// Round 4
// 705.409 us; speedup vs baseline: 1.4765x; 1.4765x over previous
//
#include <hip/hip_runtime.h>
#include <hip/hip_bf16.h>
#include <math.h>

#define HH 240
#define WW 1216
#define BATCH 4
#define PROP 6
constexpr int HW = HH * WW;            // 291,840
constexpr int NPIX = BATCH * HW;       // 1,167,360
constexpr int NPART = 1024;

typedef short short8 __attribute__((ext_vector_type(8)));
typedef float floatx4 __attribute__((ext_vector_type(4)));

__device__ __forceinline__ unsigned short f2bf(float f) {
    unsigned int u = __float_as_uint(f);
    unsigned int r = (u + 0x7FFFu + ((u >> 16) & 1u)) >> 16;
    return (unsigned short)r;
}
__device__ __forceinline__ float bf2f(unsigned short h) {
    return __uint_as_float(((unsigned int)h) << 16);
}

// LDS layout (bytes):
//   gpk    [8][10][66] u32 (hi16|lo16 bf16 pair)   @ 0      : 21120
//   offtab [3][8][4]   u32                          @ 21120  : 384
//   ptab   [9][8]      u32                          @ 21504  : 288
//   region2: wstage [32][96] f32 (12288)  |  ct 4 waves x 528 f32 (8448)
//                                                   @ 21792
constexpr int SMEM_BYTES = 21792 + 12288;   // 34080

// ---------------------------------------------------------------------------
// Propagation v4: affinity conv (25 outs x 72 ins) on MFMA (bf16 hi/lo split,
// 3-term), epilogue (sigmoid-normalize + 9-tap deformable bilinear gather)
// wave-parallel across 4 lane-groups with shfl reduction.
// Block 256 = 4 waves; tile 64 px wide x 8 rows; wave = 2 rows x 4 chunks(16px).
// ---------------------------------------------------------------------------
__global__ __launch_bounds__(256, 2) void prop_kernel(
    const float* __restrict__ featPrev,   // [B][HW]
    const float* __restrict__ gbase,      // guidance + 8k*HW; batch stride 48*HW
    const float* __restrict__ aw,         // [9][8][3][3]
    const float* __restrict__ ab,         // [9]
    const float* __restrict__ ow,         // [16][8][3][3]
    const float* __restrict__ ob,         // [16]
    const float* __restrict__ w3,         // [9]
    const float* __restrict__ b3,         // [1]
    float* __restrict__ featNext)         // [B][HW]
{
    __shared__ __attribute__((aligned(16))) unsigned char smem[SMEM_BYTES];
    uint32_t* gpk    = (uint32_t*)smem;
    uint32_t* offtab = (uint32_t*)(smem + 21120);
    uint32_t* ptab   = (uint32_t*)(smem + 21504);
    float*    wst    = (float*)(smem + 21792);
    float*    ctb    = (float*)(smem + 21792);

    const int tid = threadIdx.x;
    const int x0 = blockIdx.x * 64;
    const int y0t = blockIdx.y * 8;
    const int b = blockIdx.z;
    const float* gb = gbase + (size_t)b * (48 * HW);

    // ---- stage guidance ext tile as packed bf16 hi/lo (zero-pad OOB) ----
    for (int idx = tid; idx < 5280; idx += 256) {
        const int c = idx / 660, rem = idx - c * 660;
        const int row = rem / 66, col = rem - row * 66;
        const int gy = y0t + row - 1, gx = x0 + col - 1;
        float v = 0.0f;
        if (((unsigned)gy < (unsigned)HH) & ((unsigned)gx < (unsigned)WW))
            v = gb[c * HW + gy * WW + gx];
        const unsigned short hi = f2bf(v);
        const unsigned short lo = f2bf(v - bf2f(hi));
        gpk[idx] = ((uint32_t)hi << 16) | lo;
    }
    // ---- stage weight matrix [o(32,pad)][k(96,pad)] fp32, zeros on pad ----
    for (int idx = tid; idx < 3072; idx += 256) {
        const int o = idx / 96, k = idx - o * 96;
        float v = 0.0f;
        if (o < 25 && k < 72) {
            const int c = k / 9, t = k - 9 * c;
            v = (o < 9) ? aw[(o * 8 + c) * 9 + t] : ow[((o - 9) * 8 + c) * 9 + t];
        }
        wst[idx] = v;
    }
    // ---- offtab[s][e][g]: gpk word-offset of (c, dy, dx) for that k ----
    if (tid < 96) {
        const int s = tid >> 5, rem = tid & 31, e = rem >> 2, gq = rem & 3;
        const int k = s * 32 + gq * 8 + e;
        uint32_t off = 0;
        if (k < 72) {
            const int c = k / 9, t = k - 9 * c, dy = t / 3, dx = t - 3 * dy;
            off = (uint32_t)(c * 660 + dy * 66 + dx);
        }
        offtab[tid] = off;
    }
    // ---- ptab[t]: {ab, oyb, oxb, w3, ct_ioy, ct_iox, dy, dx} ----
    if (tid < 9) {
        const int t = tid, p = (t < 4) ? t : t - 1;
        float oyb = 0.0f, oxb = 0.0f;
        if (t != 4) { oyb = ob[2 * p]; oxb = ob[2 * p + 1]; }
        ptab[t * 8 + 0] = __float_as_uint(ab[t]);
        ptab[t * 8 + 1] = __float_as_uint(oyb);
        ptab[t * 8 + 2] = __float_as_uint(oxb);
        ptab[t * 8 + 3] = __float_as_uint(w3[t]);
        ptab[t * 8 + 4] = (t == 4) ? 15u : (uint32_t)(9 + 2 * p);
        ptab[t * 8 + 5] = (t == 4) ? 16u : (uint32_t)(10 + 2 * p);
        ptab[t * 8 + 6] = (uint32_t)(t / 3);
        ptab[t * 8 + 7] = (uint32_t)(t % 3);
    }
    __syncthreads();

    const int lane = tid & 63, wid = tid >> 6;
    const int grp = lane >> 4, l15 = lane & 15;

    // ---- A fragments: lane supplies A[m = l15][k = s*32 + grp*8 + e] ----
    short8 Ah0[3], Ah1[3], Al0[3], Al1[3];
    {
        const int kb = grp * 8;
#pragma unroll
        for (int s = 0; s < 3; ++s) {
            const float* wp0 = &wst[l15 * 96 + s * 32 + kb];
            const float* wp1 = &wst[(16 + l15) * 96 + s * 32 + kb];
            short8 h0, l0, h1, l1;
#pragma unroll
            for (int e = 0; e < 8; ++e) {
                const float v0 = wp0[e];
                const unsigned short hb0 = f2bf(v0);
                h0[e] = (short)hb0;
                l0[e] = (short)f2bf(v0 - bf2f(hb0));
                const float v1 = wp1[e];
                const unsigned short hb1 = f2bf(v1);
                h1[e] = (short)hb1;
                l1[e] = (short)f2bf(v1 - bf2f(hb1));
            }
            Ah0[s] = h0; Al0[s] = l0; Ah1[s] = h1; Al1[s] = l1;
        }
    }

    // ---- per-lane B-read byte addresses (24) ----
    uint32_t cvaddr[3][8];
#pragma unroll
    for (int s = 0; s < 3; ++s)
#pragma unroll
        for (int e = 0; e < 8; ++e)
            cvaddr[s][e] = (offtab[s * 32 + e * 4 + grp] +
                            (uint32_t)(wid * 132 + l15)) * 4u;

    // ---- per-lane tap parameters (taps 2g, 2g+1, 8) ----
    float tab_ab[3], tab_oyb[3], tab_oxb[3], tab_w3[3];
    int tab_ioy[3], tab_iox[3], tab_dy[3], tab_dx[3], tab_t[3];
#pragma unroll
    for (int j = 0; j < 3; ++j) {
        const int t = (j < 2) ? (grp * 2 + j) : 8;
        tab_t[j] = t;
        tab_ab[j]  = __uint_as_float(ptab[t * 8 + 0]);
        tab_oyb[j] = __uint_as_float(ptab[t * 8 + 1]);
        tab_oxb[j] = __uint_as_float(ptab[t * 8 + 2]);
        tab_w3[j]  = __uint_as_float(ptab[t * 8 + 3]);
        tab_ioy[j] = (int)ptab[t * 8 + 4];
        tab_iox[j] = (int)ptab[t * 8 + 5];
        tab_dy[j]  = (int)ptab[t * 8 + 6];
        tab_dx[j]  = (int)ptab[t * 8 + 7];
    }
    __syncthreads();   // all waves done reading wst before ct reuse

    float* ct = ctb + wid * 528;    // [16 px][33]
    const float* fb = featPrev + (size_t)b * HW;
    const float b3v = b3[0];
    const int ybase = y0t + wid * 2;
    const unsigned char* gpkB = (const unsigned char*)gpk;

#pragma unroll
    for (int r = 0; r < 2; ++r) {
        const int y = ybase + r;
#pragma unroll
        for (int ch = 0; ch < 4; ++ch) {
            floatx4 acc0 = {0.f, 0.f, 0.f, 0.f};
            floatx4 acc1 = {0.f, 0.f, 0.f, 0.f};
#pragma unroll
            for (int s = 0; s < 3; ++s) {
                uint32_t ev[8];
#pragma unroll
                for (int e = 0; e < 8; ++e)
                    ev[e] = *(const uint32_t*)(gpkB + cvaddr[s][e] +
                                               (r * 66 + ch * 16) * 4);
                union { uint32_t u[4]; short8 v; } bh, bl;
#pragma unroll
                for (int i = 0; i < 4; ++i) {
                    bh.u[i] = (ev[2 * i] >> 16) | (ev[2 * i + 1] & 0xFFFF0000u);
                    bl.u[i] = (ev[2 * i] & 0xFFFFu) | (ev[2 * i + 1] << 16);
                }
                acc0 = __builtin_amdgcn_mfma_f32_16x16x32_bf16(Ah0[s], bh.v, acc0, 0, 0, 0);
                acc1 = __builtin_amdgcn_mfma_f32_16x16x32_bf16(Ah1[s], bh.v, acc1, 0, 0, 0);
                acc0 = __builtin_amdgcn_mfma_f32_16x16x32_bf16(Ah0[s], bl.v, acc0, 0, 0, 0);
                acc1 = __builtin_amdgcn_mfma_f32_16x16x32_bf16(Ah1[s], bl.v, acc1, 0, 0, 0);
                acc0 = __builtin_amdgcn_mfma_f32_16x16x32_bf16(Al0[s], bh.v, acc0, 0, 0, 0);
                acc1 = __builtin_amdgcn_mfma_f32_16x16x32_bf16(Al1[s], bh.v, acc1, 0, 0, 0);
            }
            // C layout: col(px) = l15, row(o) = grp*4 + i  (+16 for Mtile1)
#pragma unroll
            for (int i = 0; i < 4; ++i) {
                ct[l15 * 33 + grp * 4 + i] = acc0[i];
                ct[l15 * 33 + 16 + grp * 4 + i] = acc1[i];
            }
            // ---- epilogue: this lane handles its 2-3 taps for px = l15 ----
            const int x = x0 + ch * 16 + l15;
            float wsum = 0.0f, res = 0.0f;
#pragma unroll
            for (int j = 0; j < 3; ++j) {
                const float a = ct[l15 * 33 + tab_t[j]] + tab_ab[j];
                float sig = 1.0f / (1.0f + __expf(-a));
                if (j == 2) sig *= 0.25f;     // tap 8 computed by all 4 groups
                float oy = ct[l15 * 33 + tab_ioy[j]] + tab_oyb[j];
                float ox = ct[l15 * 33 + tab_iox[j]] + tab_oxb[j];
                const bool t4 = (tab_t[j] == 4);
                oy = t4 ? 0.0f : oy;
                ox = t4 ? 0.0f : ox;

                const float py = (float)(y - 1 + tab_dy[j]) + oy;
                const float px = (float)(x - 1 + tab_dx[j]) + ox;
                const float fy = floorf(py), fx = floorf(px);
                const float wy = py - fy, wx = px - fx;
                const int iy = (int)fy, ix = (int)fx;
                const int iy1 = iy + 1, ix1 = ix + 1;

                const int ry0 = min(max(iy, 0), HH - 1) * WW;
                const int ry1 = min(max(iy1, 0), HH - 1) * WW;
                const int cx0 = min(max(ix, 0), WW - 1);
                const int cx1 = min(max(ix1, 0), WW - 1);
                const float v00 = fb[ry0 + cx0], v01 = fb[ry0 + cx1];
                const float v10 = fb[ry1 + cx0], v11 = fb[ry1 + cx1];

                const bool vy0 = (unsigned)iy < (unsigned)HH;
                const bool vy1 = (unsigned)iy1 < (unsigned)HH;
                const bool vx0 = (unsigned)ix < (unsigned)WW;
                const bool vx1 = (unsigned)ix1 < (unsigned)WW;
                const float wy0 = 1.0f - wy, wx0 = 1.0f - wx;

                float samp = 0.0f;
                samp = fmaf((vy0 & vx0) ? wy0 * wx0 : 0.0f, v00, samp);
                samp = fmaf((vy0 & vx1) ? wy0 * wx  : 0.0f, v01, samp);
                samp = fmaf((vy1 & vx0) ? wy  * wx0 : 0.0f, v10, samp);
                samp = fmaf((vy1 & vx1) ? wy  * wx  : 0.0f, v11, samp);

                wsum += sig;
                res = fmaf(sig * tab_w3[j], samp, res);
            }
            res += __shfl_xor(res, 16);
            res += __shfl_xor(res, 32);
            wsum += __shfl_xor(wsum, 16);
            wsum += __shfl_xor(wsum, 32);
            if (lane < 16)
                featNext[(size_t)b * HW + (size_t)y * WW + x] =
                    res / (wsum + 1e-8f) + b3v;
        }
    }
}

// ---------------------------------------------------------------------------
// Stage 1 of BN stats: per-block partial sums of y0,y1,y2 and their products.
// ---------------------------------------------------------------------------
__global__ __launch_bounds__(256) void stats_part(
    const float* __restrict__ y0s, const float* __restrict__ y1s,
    const float* __restrict__ y2s, float* __restrict__ part)
{
    float a[9] = {0, 0, 0, 0, 0, 0, 0, 0, 0};
    const int stride = gridDim.x * 256;
    for (int i = blockIdx.x * 256 + threadIdx.x; i < NPIX; i += stride) {
        const float v0 = y0s[i], v1 = y1s[i], v2 = y2s[i];
        a[0] += v0; a[1] += v1; a[2] += v2;
        a[3] = fmaf(v0, v0, a[3]); a[4] = fmaf(v0, v1, a[4]);
        a[5] = fmaf(v0, v2, a[5]); a[6] = fmaf(v1, v1, a[6]);
        a[7] = fmaf(v1, v2, a[7]); a[8] = fmaf(v2, v2, a[8]);
    }
    __shared__ float red[4][9];
    const int lane = threadIdx.x & 63, wv = threadIdx.x >> 6;
#pragma unroll
    for (int q = 0; q < 9; ++q) {
        float v = a[q];
        for (int o = 32; o; o >>= 1) v += __shfl_down(v, o, 64);
        if (lane == 0) red[wv][q] = v;
    }
    __syncthreads();
    if (threadIdx.x < 9) {
        const int q = threadIdx.x;
        part[blockIdx.x * 9 + q] = red[0][q] + red[1][q] + red[2][q] + red[3][q];
    }
}

// ---------------------------------------------------------------------------
// Stage 2: finalize per-channel BN scale/shift for sf = proj(y).
// ---------------------------------------------------------------------------
__global__ __launch_bounds__(256) void stats_final(
    const float* __restrict__ part, const float* __restrict__ proj_w,
    const float* __restrict__ bn_g, const float* __restrict__ bn_b,
    float* __restrict__ stats)
{
    float a[9] = {0, 0, 0, 0, 0, 0, 0, 0, 0};
    for (int i = threadIdx.x; i < NPART; i += 256) {
#pragma unroll
        for (int q = 0; q < 9; ++q) a[q] += part[i * 9 + q];
    }
    __shared__ float red[4][9];
    const int lane = threadIdx.x & 63, wv = threadIdx.x >> 6;
#pragma unroll
    for (int q = 0; q < 9; ++q) {
        float v = a[q];
        for (int o = 32; o; o >>= 1) v += __shfl_down(v, o, 64);
        if (lane == 0) red[wv][q] = v;
    }
    __syncthreads();
    if (threadIdx.x == 0) {
        float s[9];
#pragma unroll
        for (int q = 0; q < 9; ++q) s[q] = red[0][q] + red[1][q] + red[2][q] + red[3][q];
        const float invN = 1.0f / (float)NPIX;
        const float m0 = s[0] * invN, m1 = s[1] * invN, m2 = s[2] * invN;
        const float E00 = s[3] * invN, E01 = s[4] * invN, E02 = s[5] * invN;
        const float E11 = s[6] * invN, E12 = s[7] * invN, E22 = s[8] * invN;
#pragma unroll
        for (int c = 0; c < 6; ++c) {
            const float p0 = proj_w[c * 3], p1 = proj_w[c * 3 + 1], p2 = proj_w[c * 3 + 2];
            const float mu = p0 * m0 + p1 * m1 + p2 * m2;
            const float e2 = p0 * p0 * E00 + p1 * p1 * E11 + p2 * p2 * E22 +
                             2.0f * (p0 * p1 * E01 + p0 * p2 * E02 + p1 * p2 * E12);
            const float var = e2 - mu * mu;
            const float sc = bn_g[c] / sqrtf(var + 1e-5f);
            stats[c] = sc;
            stats[6 + c] = bn_b[c] - mu * sc;
        }
    }
}

// ---------------------------------------------------------------------------
// Fused head, tile 32x8. a1/a2 carried in registers (no LDS round-trip);
// 84 extra ring jobs fill the agg halo.
// ---------------------------------------------------------------------------
__global__ __launch_bounds__(256, 4) void head_kernel(
    const float* __restrict__ y0s, const float* __restrict__ y1s,
    const float* __restrict__ y2s, const float* __restrict__ attn,
    const float* __restrict__ stats,   // scale[6], shift[6]
    const float* __restrict__ proj_w,
    const float* __restrict__ c0_w, const float* __restrict__ c0_b,
    const float* __restrict__ cs_w, const float* __restrict__ cs_b,
    const float* __restrict__ c1_w, const float* __restrict__ c1_b,
    const float* __restrict__ c2_w, const float* __restrict__ c2_b,
    const float* __restrict__ csq_w, const float* __restrict__ csq_b,
    const float* __restrict__ cv_w, const float* __restrict__ cv_b,
    float* __restrict__ out)
{
    __shared__ float ap[22][432];    // a1_pre, ext tile 12x36 (halo 2)
    __shared__ float aggs[2][340];   // agg, tile+halo1 10x34

    const int tid = threadIdx.x;
    const int b = blockIdx.z;
    const int x0 = blockIdx.x * 32;
    const int y0t = blockIdx.y * 8;

    // ---- phase 1: a1_pre over ext tile (zero outside image = conv pad) ----
    for (int idx = tid; idx < 432; idx += 256) {
        const int eyl = idx / 36, exl = idx - eyl * 36;
        const int gy = y0t + eyl - 2, gx = x0 + exl - 2;
        float v[22];
        if (((unsigned)gy < (unsigned)HH) & ((unsigned)gx < (unsigned)WW)) {
            const size_t p = (size_t)gy * WW + gx;
            const float* abp = attn + (size_t)b * 16 * HW + p;
#pragma unroll
            for (int c = 0; c < 16; ++c)
                v[c] = fmaf(c0_w[c], abp[(size_t)c * HW], c0_b[c]);
            const float ym0 = y0s[(size_t)b * HW + p];
            const float ym1 = y1s[(size_t)b * HW + p];
            const float ym2 = y2s[(size_t)b * HW + p];
#pragma unroll
            for (int j = 0; j < 6; ++j) {
                const float sraw = proj_w[j * 3] * ym0 + proj_w[j * 3 + 1] * ym1 +
                                   proj_w[j * 3 + 2] * ym2;
                float sf = fmaf(stats[j], sraw, stats[6 + j]);
                sf = sf > 0.0f ? sf : 0.2f * sf;
                v[16 + j] = fmaf(c0_w[16 + j], sf, c0_b[16 + j]);
            }
        } else {
#pragma unroll
            for (int c = 0; c < 22; ++c) v[c] = 0.0f;
        }
#pragma unroll
        for (int c = 0; c < 22; ++c) ap[c][idx] = v[c];
    }
    __syncthreads();

    // computes a1[11], a2[11] at agg coords (ay,ax)
    auto compute_px = [&](int ay, int ax, float* a1, float* a2) {
        const int ey = ay + 1, ex = ax + 1;   // ext coords
#pragma unroll
        for (int j = 0; j < 11; ++j) { a1[j] = c1_b[j]; a2[j] = c2_b[j]; }
#pragma unroll
        for (int c = 0; c < 22; ++c) {
            float dw = cs_b[c];
            float ctr = 0.0f;
#pragma unroll
            for (int t = 0; t < 9; ++t) {
                const float av = ap[c][(ey + t / 3 - 1) * 36 + (ex + t % 3 - 1)];
                dw = fmaf(cs_w[c * 9 + t], av, dw);
                if (t == 4) ctr = av;
            }
#pragma unroll
            for (int j = 0; j < 11; ++j) {
                a1[j] = fmaf(c1_w[j * 22 + c], ctr, a1[j]);
                a2[j] = fmaf(c2_w[j * 22 + c], dw, a2[j]);
            }
        }
    };

    // ---- phase 2a: ring jobs (84 halo pixels of the 10x34 agg region) ----
    if (tid < 84) {
        int ay, ax;
        if (tid < 34)      { ay = 0; ax = tid; }
        else if (tid < 68) { ay = 9; ax = tid - 34; }
        else { const int s = tid - 68; ay = 1 + (s >> 1); ax = (s & 1) ? 33 : 0; }
        const int gy = y0t + ay - 1, gx = x0 + ax - 1;
        float m0 = 0.0f, m1 = 0.0f;
        if (((unsigned)gy < (unsigned)HH) & ((unsigned)gx < (unsigned)WW)) {
            float a1h[11], a2h[11];
            compute_px(ay, ax, a1h, a2h);
            float s = 0.0f, mx = -INFINITY;
#pragma unroll
            for (int j = 0; j < 11; ++j) {
                s += a1h[j] + a2h[j];
                mx = fmaxf(mx, fmaxf(a1h[j], a2h[j]));
            }
            m0 = s * (1.0f / 22.0f);
            m1 = mx;
        }
        aggs[0][ay * 34 + ax] = m0;
        aggs[1][ay * 34 + ax] = m1;
    }

    // ---- phase 2b: center pixel, keep a1/a2 in registers ----
    const int ty = tid >> 5, tx = tid & 31;
    const int ay = ty + 1, ax = tx + 1;
    float a1[11], a2[11];
    compute_px(ay, ax, a1, a2);
    {
        float s = 0.0f, mx = -INFINITY;
#pragma unroll
        for (int j = 0; j < 11; ++j) {
            s += a1[j] + a2[j];
            mx = fmaxf(mx, fmaxf(a1[j], a2[j]));
        }
        aggs[0][ay * 34 + ax] = s * (1.0f / 22.0f);
        aggs[1][ay * 34 + ax] = mx;
    }
    __syncthreads();

    // ---- phase 3: sigmoid gate + cv + final dot with y ----
    float z0 = csq_b[0], z1 = csq_b[1];
#pragma unroll
    for (int t = 0; t < 9; ++t) {
        const int ai = (ay + t / 3 - 1) * 34 + (ax + t % 3 - 1);
        const float g0 = aggs[0][ai], g1 = aggs[1][ai];
        z0 = fmaf(csq_w[t], g0, fmaf(csq_w[9 + t], g1, z0));
        z1 = fmaf(csq_w[18 + t], g0, fmaf(csq_w[27 + t], g1, z1));
    }
    const float s0 = 1.0f / (1.0f + __expf(-z0));
    const float s1 = 1.0f / (1.0f + __expf(-z1));
    float v0 = cv_b[0], v1 = cv_b[1], v2 = cv_b[2];
#pragma unroll
    for (int j = 0; j < 11; ++j) {
        const float av = a1[j] * s0 + a2[j] * s1;
        v0 = fmaf(cv_w[j], av, v0);
        v1 = fmaf(cv_w[11 + j], av, v1);
        v2 = fmaf(cv_w[22 + j], av, v2);
    }
    const size_t p = (size_t)b * HW + (size_t)(y0t + ty) * WW + (x0 + tx);
    out[p] = y0s[p] * v0 + y1s[p] * v1 + y2s[p] * v2;
}

// ---------------------------------------------------------------------------
extern "C" void kernel_launch(void* const* d_in, const int* in_sizes, int n_in,
                              void* d_out, int out_size, void* d_ws, size_t ws_size,
                              hipStream_t stream)
{
    (void)in_sizes; (void)n_in; (void)out_size; (void)ws_size;
    const float* feat_init = (const float*)d_in[0];
    const float* guidance  = (const float*)d_in[1];
    const float* attn      = (const float*)d_in[2];
    const float* aff_w_w   = (const float*)d_in[4];
    const float* aff_w_b   = (const float*)d_in[5];
    const float* aff_o_w   = (const float*)d_in[6];
    const float* aff_o_b   = (const float*)d_in[7];
    const float* w3        = (const float*)d_in[8];
    const float* b3        = (const float*)d_in[9];
    const float* proj_w    = (const float*)d_in[10];
    const float* bn_g      = (const float*)d_in[11];
    const float* bn_b      = (const float*)d_in[12];
    const float* c0_w      = (const float*)d_in[13];
    const float* c0_b      = (const float*)d_in[14];
    const float* cs_w      = (const float*)d_in[15];
    const float* cs_b      = (const float*)d_in[16];
    const float* c1_w      = (const float*)d_in[17];
    const float* c1_b      = (const float*)d_in[18];
    const float* c2_w      = (const float*)d_in[19];
    const float* c2_b      = (const float*)d_in[20];
    const float* csq_w     = (const float*)d_in[21];
    const float* csq_b     = (const float*)d_in[22];
    const float* cv_w      = (const float*)d_in[23];
    const float* cv_b      = (const float*)d_in[24];

    float* ws = (float*)d_ws;
    float* slot[5];
    for (int i = 0; i < 5; ++i) slot[i] = ws + (size_t)i * NPIX;
    float* part  = ws + (size_t)5 * NPIX;
    float* stats = part + (size_t)9 * NPART;

    const dim3 blk(256);
    const dim3 gp(WW / 64, HH / 8, BATCH);

    // propagation chain; keep feats[3],[4],[5] in slots 2,3,4
    const int dst_ids[PROP] = {0, 1, 0, 2, 3, 4};
    const float* src = feat_init;
    for (int k = 0; k < PROP; ++k) {
        float* dst = slot[dst_ids[k]];
        prop_kernel<<<gp, blk, 0, stream>>>(
            src, guidance + (size_t)8 * k * HW,
            aff_w_w + (size_t)k * 648, aff_w_b + (size_t)k * 9,
            aff_o_w + (size_t)k * 1152, aff_o_b + (size_t)k * 16,
            w3, b3, dst);
        src = dst;
    }

    stats_part<<<dim3(NPART), blk, 0, stream>>>(slot[2], slot[3], slot[4], part);
    stats_final<<<dim3(1), blk, 0, stream>>>(part, proj_w, bn_g, bn_b, stats);

    head_kernel<<<dim3(WW / 32, HH / 8, BATCH), blk, 0, stream>>>(
        slot[2], slot[3], slot[4], attn, stats, proj_w,
        c0_w, c0_b, cs_w, cs_b, c1_w, c1_b, c2_w, c2_b,
        csq_w, csq_b, cv_w, cv_b, (float*)d_out);
}

// Round 5
// 642.039 us; speedup vs baseline: 1.6223x; 1.0987x over previous
//
#include <hip/hip_runtime.h>
#include <hip/hip_bf16.h>
#include <math.h>

#define HH 240
#define WW 1216
#define BATCH 4
#define PROP 6
constexpr int HW = HH * WW;            // 291,840
constexpr int NPIX = BATCH * HW;       // 1,167,360
constexpr int NPART = 1024;

typedef short short8 __attribute__((ext_vector_type(8)));
typedef float floatx4 __attribute__((ext_vector_type(4)));

__device__ __forceinline__ unsigned short f2bf(float f) {
    unsigned int u = __float_as_uint(f);
    unsigned int r = (u + 0x7FFFu + ((u >> 16) & 1u)) >> 16;
    return (unsigned short)r;
}
__device__ __forceinline__ float bf2f(unsigned short h) {
    return __uint_as_float(((unsigned int)h) << 16);
}

// LDS layout (bytes):
//   gpk    [8][10][66] u32 (hi16|lo16 bf16 pair)   @ 0      : 21120
//   offtab [3][8][4]   u32                          @ 21120  : 384
//   region2 @ 21792: wst [32][96] f32 (12288, dead after A-build)
//                    | ct 4 waves x [64][27] f32 (27648)
constexpr int CT_STRIDE = 27;          // gcd(27,32)=1 -> conflict-free col reads
constexpr int SMEM_BYTES = 21792 + 4 * 64 * CT_STRIDE * 4;   // 49440

// ---------------------------------------------------------------------------
// Propagation v5: affinity conv (25x72) on MFMA (bf16 hi/lo 3-term split).
// Wave handles 2 rows of 64 px: 4 MFMA chunks back-to-back -> ct[64][27] in
// LDS -> lane-owns-pixel epilogue (full 9-tap deformable bilinear, serial,
// no cross-lane reduction, coalesced row store).
// ---------------------------------------------------------------------------
__global__ __launch_bounds__(256, 3) void prop_kernel(
    const float* __restrict__ featPrev,   // [B][HW]
    const float* __restrict__ gbase,      // guidance + 8k*HW; batch stride 48*HW
    const float* __restrict__ aw,         // [9][8][3][3]
    const float* __restrict__ ab,         // [9]
    const float* __restrict__ ow,         // [16][8][3][3]
    const float* __restrict__ ob,         // [16]
    const float* __restrict__ w3,         // [9]
    const float* __restrict__ b3,         // [1]
    float* __restrict__ featNext)         // [B][HW]
{
    __shared__ __attribute__((aligned(16))) unsigned char smem[SMEM_BYTES];
    uint32_t* gpk    = (uint32_t*)smem;
    uint32_t* offtab = (uint32_t*)(smem + 21120);
    float*    wst    = (float*)(smem + 21792);
    float*    ctb    = (float*)(smem + 21792);

    const int tid = threadIdx.x;
    const int x0 = blockIdx.x * 64;
    const int y0t = blockIdx.y * 8;
    const int b = blockIdx.z;
    const float* gb = gbase + (size_t)b * (48 * HW);

    // ---- stage guidance ext tile as packed bf16 hi/lo (zero-pad OOB) ----
    for (int idx = tid; idx < 5280; idx += 256) {
        const int c = idx / 660, rem = idx - c * 660;
        const int row = rem / 66, col = rem - row * 66;
        const int gy = y0t + row - 1, gx = x0 + col - 1;
        float v = 0.0f;
        if (((unsigned)gy < (unsigned)HH) & ((unsigned)gx < (unsigned)WW))
            v = gb[c * HW + gy * WW + gx];
        const unsigned short hi = f2bf(v);
        const unsigned short lo = f2bf(v - bf2f(hi));
        gpk[idx] = ((uint32_t)hi << 16) | lo;
    }
    // ---- stage weight matrix [o(32,pad)][k(96,pad)] fp32, zeros on pad ----
    for (int idx = tid; idx < 3072; idx += 256) {
        const int o = idx / 96, k = idx - o * 96;
        float v = 0.0f;
        if (o < 25 && k < 72) {
            const int c = k / 9, t = k - 9 * c;
            v = (o < 9) ? aw[(o * 8 + c) * 9 + t] : ow[((o - 9) * 8 + c) * 9 + t];
        }
        wst[idx] = v;
    }
    // ---- offtab[s][e][g]: gpk word-offset of (c, dy, dx) for that k ----
    if (tid < 96) {
        const int s = tid >> 5, rem = tid & 31, e = rem >> 2, gq = rem & 3;
        const int k = s * 32 + gq * 8 + e;
        uint32_t off = 0;
        if (k < 72) {
            const int c = k / 9, t = k - 9 * c, dy = t / 3, dx = t - 3 * dy;
            off = (uint32_t)(c * 660 + dy * 66 + dx);
        }
        offtab[tid] = off;
    }
    __syncthreads();

    const int lane = tid & 63, wid = tid >> 6;
    const int grp = lane >> 4, l15 = lane & 15;

    // ---- A fragments: lane supplies A[m = l15][k = s*32 + grp*8 + e] ----
    short8 Ah0[3], Ah1[3], Al0[3], Al1[3];
    {
        const int kb = grp * 8;
#pragma unroll
        for (int s = 0; s < 3; ++s) {
            const float* wp0 = &wst[l15 * 96 + s * 32 + kb];
            const float* wp1 = &wst[(16 + l15) * 96 + s * 32 + kb];
            short8 h0, l0, h1, l1;
#pragma unroll
            for (int e = 0; e < 8; ++e) {
                const float v0 = wp0[e];
                const unsigned short hb0 = f2bf(v0);
                h0[e] = (short)hb0;
                l0[e] = (short)f2bf(v0 - bf2f(hb0));
                const float v1 = wp1[e];
                const unsigned short hb1 = f2bf(v1);
                h1[e] = (short)hb1;
                l1[e] = (short)f2bf(v1 - bf2f(hb1));
            }
            Ah0[s] = h0; Al0[s] = l0; Ah1[s] = h1; Al1[s] = l1;
        }
    }

    // ---- per-lane B-read byte addresses (24) ----
    uint32_t cvaddr[3][8];
#pragma unroll
    for (int s = 0; s < 3; ++s)
#pragma unroll
        for (int e = 0; e < 8; ++e)
            cvaddr[s][e] = (offtab[s * 32 + e * 4 + grp] +
                            (uint32_t)(wid * 132 + l15)) * 4u;

    // ---- uniform epilogue params (s_loads) ----
    float abv[9], w3v[9], obv[16];
#pragma unroll
    for (int t = 0; t < 9; ++t) { abv[t] = ab[t]; w3v[t] = w3[t]; }
#pragma unroll
    for (int o = 0; o < 16; ++o) obv[o] = ob[o];
    const float b3v = b3[0];

    __syncthreads();   // all waves done reading wst before ct reuse

    float* ct = ctb + wid * (64 * CT_STRIDE);
    const float* fb = featPrev + (size_t)b * HW;
    const int ybase = y0t + wid * 2;
    const unsigned char* gpkB = (const unsigned char*)gpk;

#pragma unroll 1
    for (int r = 0; r < 2; ++r) {
        const int y = ybase + r;
        // ---- 4 MFMA chunks back-to-back: conv outputs for the 64-px row ----
#pragma unroll
        for (int ch = 0; ch < 4; ++ch) {
            floatx4 acc0 = {0.f, 0.f, 0.f, 0.f};
            floatx4 acc1 = {0.f, 0.f, 0.f, 0.f};
#pragma unroll
            for (int s = 0; s < 3; ++s) {
                uint32_t ev[8];
#pragma unroll
                for (int e = 0; e < 8; ++e)
                    ev[e] = *(const uint32_t*)(gpkB + cvaddr[s][e] +
                                               (r * 66 + ch * 16) * 4);
                union { uint32_t u[4]; short8 v; } bh, bl;
#pragma unroll
                for (int i = 0; i < 4; ++i) {
                    bh.u[i] = (ev[2 * i] >> 16) | (ev[2 * i + 1] & 0xFFFF0000u);
                    bl.u[i] = (ev[2 * i] & 0xFFFFu) | (ev[2 * i + 1] << 16);
                }
                acc0 = __builtin_amdgcn_mfma_f32_16x16x32_bf16(Ah0[s], bh.v, acc0, 0, 0, 0);
                acc1 = __builtin_amdgcn_mfma_f32_16x16x32_bf16(Ah1[s], bh.v, acc1, 0, 0, 0);
                acc0 = __builtin_amdgcn_mfma_f32_16x16x32_bf16(Ah0[s], bl.v, acc0, 0, 0, 0);
                acc1 = __builtin_amdgcn_mfma_f32_16x16x32_bf16(Ah1[s], bl.v, acc1, 0, 0, 0);
                acc0 = __builtin_amdgcn_mfma_f32_16x16x32_bf16(Al0[s], bh.v, acc0, 0, 0, 0);
                acc1 = __builtin_amdgcn_mfma_f32_16x16x32_bf16(Al1[s], bh.v, acc1, 0, 0, 0);
            }
            // C layout: col(px) = l15, row(o) = grp*4 + i  (+16 for Mtile1)
            const int pxb = (ch * 16 + l15) * CT_STRIDE;
#pragma unroll
            for (int i = 0; i < 4; ++i) {
                ct[pxb + grp * 4 + i] = acc0[i];
                if (grp * 4 + i < 9)                    // only o=16..24 valid
                    ct[pxb + 16 + grp * 4 + i] = acc1[i];
            }
        }

        // ---- epilogue: lane owns pixel x0+lane of row y ----
        const float* cb = ct + lane * CT_STRIDE;
        float av[25];
#pragma unroll
        for (int o = 0; o < 25; ++o) av[o] = cb[o];

        float wg[9], wsum = 1e-8f;
#pragma unroll
        for (int t = 0; t < 9; ++t) {
            const float s = 1.0f / (1.0f + __expf(-(av[t] + abv[t])));
            wg[t] = s;
            wsum += s;
        }
        const float winv = 1.0f / wsum;
        const int x = x0 + lane;

        float sum = 0.0f;
#pragma unroll
        for (int t = 0; t < 9; ++t) {
            float oy, ox;
            if (t < 4)       { oy = av[9 + 2 * t] + obv[2 * t];
                               ox = av[10 + 2 * t] + obv[2 * t + 1]; }
            else if (t == 4) { oy = 0.0f; ox = 0.0f; }
            else             { oy = av[7 + 2 * t] + obv[2 * t - 2];
                               ox = av[8 + 2 * t] + obv[2 * t - 1]; }

            const float py = (float)(y - 1 + (t / 3)) + oy;
            const float px = (float)(x - 1 + (t % 3)) + ox;
            const float fy = floorf(py), fx = floorf(px);
            const float wy = py - fy, wx = px - fx;
            const int iy = (int)fy, ix = (int)fx;
            const int iy1 = iy + 1, ix1 = ix + 1;

            const int ry0 = min(max(iy, 0), HH - 1) * WW;
            const int ry1 = min(max(iy1, 0), HH - 1) * WW;
            const int cx0 = min(max(ix, 0), WW - 1);
            const int cx1 = min(max(ix1, 0), WW - 1);
            const float v00 = fb[ry0 + cx0], v01 = fb[ry0 + cx1];
            const float v10 = fb[ry1 + cx0], v11 = fb[ry1 + cx1];

            const bool vy0 = (unsigned)iy < (unsigned)HH;
            const bool vy1 = (unsigned)iy1 < (unsigned)HH;
            const bool vx0 = (unsigned)ix < (unsigned)WW;
            const bool vx1 = (unsigned)ix1 < (unsigned)WW;
            const float wy0 = 1.0f - wy, wx0 = 1.0f - wx;

            float s = 0.0f;
            s = fmaf((vy0 & vx0) ? wy0 * wx0 : 0.0f, v00, s);
            s = fmaf((vy0 & vx1) ? wy0 * wx  : 0.0f, v01, s);
            s = fmaf((vy1 & vx0) ? wy  * wx0 : 0.0f, v10, s);
            s = fmaf((vy1 & vx1) ? wy  * wx  : 0.0f, v11, s);

            sum = fmaf(wg[t] * w3v[t], s, sum);
        }
        featNext[(size_t)b * HW + (size_t)y * WW + x] = fmaf(winv, sum, b3v);
    }
}

// ---------------------------------------------------------------------------
// Stage 1 of BN stats: per-block partial sums of y0,y1,y2 and their products.
// ---------------------------------------------------------------------------
__global__ __launch_bounds__(256) void stats_part(
    const float* __restrict__ y0s, const float* __restrict__ y1s,
    const float* __restrict__ y2s, float* __restrict__ part)
{
    float a[9] = {0, 0, 0, 0, 0, 0, 0, 0, 0};
    const int stride = gridDim.x * 256;
    for (int i = blockIdx.x * 256 + threadIdx.x; i < NPIX; i += stride) {
        const float v0 = y0s[i], v1 = y1s[i], v2 = y2s[i];
        a[0] += v0; a[1] += v1; a[2] += v2;
        a[3] = fmaf(v0, v0, a[3]); a[4] = fmaf(v0, v1, a[4]);
        a[5] = fmaf(v0, v2, a[5]); a[6] = fmaf(v1, v1, a[6]);
        a[7] = fmaf(v1, v2, a[7]); a[8] = fmaf(v2, v2, a[8]);
    }
    __shared__ float red[4][9];
    const int lane = threadIdx.x & 63, wv = threadIdx.x >> 6;
#pragma unroll
    for (int q = 0; q < 9; ++q) {
        float v = a[q];
        for (int o = 32; o; o >>= 1) v += __shfl_down(v, o, 64);
        if (lane == 0) red[wv][q] = v;
    }
    __syncthreads();
    if (threadIdx.x < 9) {
        const int q = threadIdx.x;
        part[blockIdx.x * 9 + q] = red[0][q] + red[1][q] + red[2][q] + red[3][q];
    }
}

// ---------------------------------------------------------------------------
// Stage 2: finalize per-channel BN scale/shift for sf = proj(y).
// ---------------------------------------------------------------------------
__global__ __launch_bounds__(256) void stats_final(
    const float* __restrict__ part, const float* __restrict__ proj_w,
    const float* __restrict__ bn_g, const float* __restrict__ bn_b,
    float* __restrict__ stats)
{
    float a[9] = {0, 0, 0, 0, 0, 0, 0, 0, 0};
    for (int i = threadIdx.x; i < NPART; i += 256) {
#pragma unroll
        for (int q = 0; q < 9; ++q) a[q] += part[i * 9 + q];
    }
    __shared__ float red[4][9];
    const int lane = threadIdx.x & 63, wv = threadIdx.x >> 6;
#pragma unroll
    for (int q = 0; q < 9; ++q) {
        float v = a[q];
        for (int o = 32; o; o >>= 1) v += __shfl_down(v, o, 64);
        if (lane == 0) red[wv][q] = v;
    }
    __syncthreads();
    if (threadIdx.x == 0) {
        float s[9];
#pragma unroll
        for (int q = 0; q < 9; ++q) s[q] = red[0][q] + red[1][q] + red[2][q] + red[3][q];
        const float invN = 1.0f / (float)NPIX;
        const float m0 = s[0] * invN, m1 = s[1] * invN, m2 = s[2] * invN;
        const float E00 = s[3] * invN, E01 = s[4] * invN, E02 = s[5] * invN;
        const float E11 = s[6] * invN, E12 = s[7] * invN, E22 = s[8] * invN;
#pragma unroll
        for (int c = 0; c < 6; ++c) {
            const float p0 = proj_w[c * 3], p1 = proj_w[c * 3 + 1], p2 = proj_w[c * 3 + 2];
            const float mu = p0 * m0 + p1 * m1 + p2 * m2;
            const float e2 = p0 * p0 * E00 + p1 * p1 * E11 + p2 * p2 * E22 +
                             2.0f * (p0 * p1 * E01 + p0 * p2 * E02 + p1 * p2 * E12);
            const float var = e2 - mu * mu;
            const float sc = bn_g[c] / sqrtf(var + 1e-5f);
            stats[c] = sc;
            stats[6 + c] = bn_b[c] - mu * sc;
        }
    }
}

// ---------------------------------------------------------------------------
// Fused head, tile 32x8. a1/a2 carried in registers (no LDS round-trip);
// 84 extra ring jobs fill the agg halo.
// ---------------------------------------------------------------------------
__global__ __launch_bounds__(256, 4) void head_kernel(
    const float* __restrict__ y0s, const float* __restrict__ y1s,
    const float* __restrict__ y2s, const float* __restrict__ attn,
    const float* __restrict__ stats,   // scale[6], shift[6]
    const float* __restrict__ proj_w,
    const float* __restrict__ c0_w, const float* __restrict__ c0_b,
    const float* __restrict__ cs_w, const float* __restrict__ cs_b,
    const float* __restrict__ c1_w, const float* __restrict__ c1_b,
    const float* __restrict__ c2_w, const float* __restrict__ c2_b,
    const float* __restrict__ csq_w, const float* __restrict__ csq_b,
    const float* __restrict__ cv_w, const float* __restrict__ cv_b,
    float* __restrict__ out)
{
    __shared__ float ap[22][432];    // a1_pre, ext tile 12x36 (halo 2)
    __shared__ float aggs[2][340];   // agg, tile+halo1 10x34

    const int tid = threadIdx.x;
    const int b = blockIdx.z;
    const int x0 = blockIdx.x * 32;
    const int y0t = blockIdx.y * 8;

    // ---- phase 1: a1_pre over ext tile (zero outside image = conv pad) ----
    for (int idx = tid; idx < 432; idx += 256) {
        const int eyl = idx / 36, exl = idx - eyl * 36;
        const int gy = y0t + eyl - 2, gx = x0 + exl - 2;
        float v[22];
        if (((unsigned)gy < (unsigned)HH) & ((unsigned)gx < (unsigned)WW)) {
            const size_t p = (size_t)gy * WW + gx;
            const float* abp = attn + (size_t)b * 16 * HW + p;
#pragma unroll
            for (int c = 0; c < 16; ++c)
                v[c] = fmaf(c0_w[c], abp[(size_t)c * HW], c0_b[c]);
            const float ym0 = y0s[(size_t)b * HW + p];
            const float ym1 = y1s[(size_t)b * HW + p];
            const float ym2 = y2s[(size_t)b * HW + p];
#pragma unroll
            for (int j = 0; j < 6; ++j) {
                const float sraw = proj_w[j * 3] * ym0 + proj_w[j * 3 + 1] * ym1 +
                                   proj_w[j * 3 + 2] * ym2;
                float sf = fmaf(stats[j], sraw, stats[6 + j]);
                sf = sf > 0.0f ? sf : 0.2f * sf;
                v[16 + j] = fmaf(c0_w[16 + j], sf, c0_b[16 + j]);
            }
        } else {
#pragma unroll
            for (int c = 0; c < 22; ++c) v[c] = 0.0f;
        }
#pragma unroll
        for (int c = 0; c < 22; ++c) ap[c][idx] = v[c];
    }
    __syncthreads();

    // computes a1[11], a2[11] at agg coords (ay,ax)
    auto compute_px = [&](int ay, int ax, float* a1, float* a2) {
        const int ey = ay + 1, ex = ax + 1;   // ext coords
#pragma unroll
        for (int j = 0; j < 11; ++j) { a1[j] = c1_b[j]; a2[j] = c2_b[j]; }
#pragma unroll
        for (int c = 0; c < 22; ++c) {
            float dw = cs_b[c];
            float ctr = 0.0f;
#pragma unroll
            for (int t = 0; t < 9; ++t) {
                const float av = ap[c][(ey + t / 3 - 1) * 36 + (ex + t % 3 - 1)];
                dw = fmaf(cs_w[c * 9 + t], av, dw);
                if (t == 4) ctr = av;
            }
#pragma unroll
            for (int j = 0; j < 11; ++j) {
                a1[j] = fmaf(c1_w[j * 22 + c], ctr, a1[j]);
                a2[j] = fmaf(c2_w[j * 22 + c], dw, a2[j]);
            }
        }
    };

    // ---- phase 2a: ring jobs (84 halo pixels of the 10x34 agg region) ----
    if (tid < 84) {
        int ay, ax;
        if (tid < 34)      { ay = 0; ax = tid; }
        else if (tid < 68) { ay = 9; ax = tid - 34; }
        else { const int s = tid - 68; ay = 1 + (s >> 1); ax = (s & 1) ? 33 : 0; }
        const int gy = y0t + ay - 1, gx = x0 + ax - 1;
        float m0 = 0.0f, m1 = 0.0f;
        if (((unsigned)gy < (unsigned)HH) & ((unsigned)gx < (unsigned)WW)) {
            float a1h[11], a2h[11];
            compute_px(ay, ax, a1h, a2h);
            float s = 0.0f, mx = -INFINITY;
#pragma unroll
            for (int j = 0; j < 11; ++j) {
                s += a1h[j] + a2h[j];
                mx = fmaxf(mx, fmaxf(a1h[j], a2h[j]));
            }
            m0 = s * (1.0f / 22.0f);
            m1 = mx;
        }
        aggs[0][ay * 34 + ax] = m0;
        aggs[1][ay * 34 + ax] = m1;
    }

    // ---- phase 2b: center pixel, keep a1/a2 in registers ----
    const int ty = tid >> 5, tx = tid & 31;
    const int ay = ty + 1, ax = tx + 1;
    float a1[11], a2[11];
    compute_px(ay, ax, a1, a2);
    {
        float s = 0.0f, mx = -INFINITY;
#pragma unroll
        for (int j = 0; j < 11; ++j) {
            s += a1[j] + a2[j];
            mx = fmaxf(mx, fmaxf(a1[j], a2[j]));
        }
        aggs[0][ay * 34 + ax] = s * (1.0f / 22.0f);
        aggs[1][ay * 34 + ax] = mx;
    }
    __syncthreads();

    // ---- phase 3: sigmoid gate + cv + final dot with y ----
    float z0 = csq_b[0], z1 = csq_b[1];
#pragma unroll
    for (int t = 0; t < 9; ++t) {
        const int ai = (ay + t / 3 - 1) * 34 + (ax + t % 3 - 1);
        const float g0 = aggs[0][ai], g1 = aggs[1][ai];
        z0 = fmaf(csq_w[t], g0, fmaf(csq_w[9 + t], g1, z0));
        z1 = fmaf(csq_w[18 + t], g0, fmaf(csq_w[27 + t], g1, z1));
    }
    const float s0 = 1.0f / (1.0f + __expf(-z0));
    const float s1 = 1.0f / (1.0f + __expf(-z1));
    float v0 = cv_b[0], v1 = cv_b[1], v2 = cv_b[2];
#pragma unroll
    for (int j = 0; j < 11; ++j) {
        const float av = a1[j] * s0 + a2[j] * s1;
        v0 = fmaf(cv_w[j], av, v0);
        v1 = fmaf(cv_w[11 + j], av, v1);
        v2 = fmaf(cv_w[22 + j], av, v2);
    }
    const size_t p = (size_t)b * HW + (size_t)(y0t + ty) * WW + (x0 + tx);
    out[p] = y0s[p] * v0 + y1s[p] * v1 + y2s[p] * v2;
}

// ---------------------------------------------------------------------------
extern "C" void kernel_launch(void* const* d_in, const int* in_sizes, int n_in,
                              void* d_out, int out_size, void* d_ws, size_t ws_size,
                              hipStream_t stream)
{
    (void)in_sizes; (void)n_in; (void)out_size; (void)ws_size;
    const float* feat_init = (const float*)d_in[0];
    const float* guidance  = (const float*)d_in[1];
    const float* attn      = (const float*)d_in[2];
    const float* aff_w_w   = (const float*)d_in[4];
    const float* aff_w_b   = (const float*)d_in[5];
    const float* aff_o_w   = (const float*)d_in[6];
    const float* aff_o_b   = (const float*)d_in[7];
    const float* w3        = (const float*)d_in[8];
    const float* b3        = (const float*)d_in[9];
    const float* proj_w    = (const float*)d_in[10];
    const float* bn_g      = (const float*)d_in[11];
    const float* bn_b      = (const float*)d_in[12];
    const float* c0_w      = (const float*)d_in[13];
    const float* c0_b      = (const float*)d_in[14];
    const float* cs_w      = (const float*)d_in[15];
    const float* cs_b      = (const float*)d_in[16];
    const float* c1_w      = (const float*)d_in[17];
    const float* c1_b      = (const float*)d_in[18];
    const float* c2_w      = (const float*)d_in[19];
    const float* c2_b      = (const float*)d_in[20];
    const float* csq_w     = (const float*)d_in[21];
    const float* csq_b     = (const float*)d_in[22];
    const float* cv_w      = (const float*)d_in[23];
    const float* cv_b      = (const float*)d_in[24];

    float* ws = (float*)d_ws;
    float* slot[5];
    for (int i = 0; i < 5; ++i) slot[i] = ws + (size_t)i * NPIX;
    float* part  = ws + (size_t)5 * NPIX;
    float* stats = part + (size_t)9 * NPART;

    const dim3 blk(256);
    const dim3 gp(WW / 64, HH / 8, BATCH);

    // propagation chain; keep feats[3],[4],[5] in slots 2,3,4
    const int dst_ids[PROP] = {0, 1, 0, 2, 3, 4};
    const float* src = feat_init;
    for (int k = 0; k < PROP; ++k) {
        float* dst = slot[dst_ids[k]];
        prop_kernel<<<gp, blk, 0, stream>>>(
            src, guidance + (size_t)8 * k * HW,
            aff_w_w + (size_t)k * 648, aff_w_b + (size_t)k * 9,
            aff_o_w + (size_t)k * 1152, aff_o_b + (size_t)k * 16,
            w3, b3, dst);
        src = dst;
    }

    stats_part<<<dim3(NPART), blk, 0, stream>>>(slot[2], slot[3], slot[4], part);
    stats_final<<<dim3(1), blk, 0, stream>>>(part, proj_w, bn_g, bn_b, stats);

    head_kernel<<<dim3(WW / 32, HH / 8, BATCH), blk, 0, stream>>>(
        slot[2], slot[3], slot[4], attn, stats, proj_w,
        c0_w, c0_b, cs_w, cs_b, c1_w, c1_b, c2_w, c2_b,
        csq_w, csq_b, cv_w, cv_b, (float*)d_out);
}

// Round 6
// 626.343 us; speedup vs baseline: 1.6629x; 1.0251x over previous
//
#include <hip/hip_runtime.h>
#include <hip/hip_bf16.h>
#include <math.h>

#define HH 240
#define WW 1216
#define BATCH 4
#define PROP 6
constexpr int HW = HH * WW;            // 291,840
constexpr int NPIX = BATCH * HW;       // 1,167,360
constexpr int NPART = 1024;

typedef short short8 __attribute__((ext_vector_type(8)));
typedef float floatx4 __attribute__((ext_vector_type(4)));

__device__ __forceinline__ unsigned short f2bf(float f) {
    unsigned int u = __float_as_uint(f);
    unsigned int r = (u + 0x7FFFu + ((u >> 16) & 1u)) >> 16;
    return (unsigned short)r;
}
__device__ __forceinline__ float bf2f(unsigned short h) {
    return __uint_as_float(((unsigned int)h) << 16);
}

// LDS layout (bytes):
//   gpk    [8][10][66] u32 (hi16|lo16 bf16 pair)   @ 0      : 21120
//   offtab [3][8][4]   u32                          @ 21120  : 384
//   region2 @ 21792: wst [32][96] f32 (12288, dead after A-build)
//                    | ct 4 waves x [64][27] f32 (27648)
constexpr int CT_STRIDE = 27;          // gcd(27,32)=1 -> conflict-free col reads
constexpr int SMEM_BYTES = 21792 + 4 * 64 * CT_STRIDE * 4;   // 49440

// ---------------------------------------------------------------------------
// Propagation v5 (unchanged from round 4): affinity conv (25x72) on MFMA
// (bf16 hi/lo 3-term split); lane-owns-pixel epilogue.
// ---------------------------------------------------------------------------
__global__ __launch_bounds__(256, 3) void prop_kernel(
    const float* __restrict__ featPrev,   // [B][HW]
    const float* __restrict__ gbase,      // guidance + 8k*HW; batch stride 48*HW
    const float* __restrict__ aw,         // [9][8][3][3]
    const float* __restrict__ ab,         // [9]
    const float* __restrict__ ow,         // [16][8][3][3]
    const float* __restrict__ ob,         // [16]
    const float* __restrict__ w3,         // [9]
    const float* __restrict__ b3,         // [1]
    float* __restrict__ featNext)         // [B][HW]
{
    __shared__ __attribute__((aligned(16))) unsigned char smem[SMEM_BYTES];
    uint32_t* gpk    = (uint32_t*)smem;
    uint32_t* offtab = (uint32_t*)(smem + 21120);
    float*    wst    = (float*)(smem + 21792);
    float*    ctb    = (float*)(smem + 21792);

    const int tid = threadIdx.x;
    const int x0 = blockIdx.x * 64;
    const int y0t = blockIdx.y * 8;
    const int b = blockIdx.z;
    const float* gb = gbase + (size_t)b * (48 * HW);

    // ---- stage guidance ext tile as packed bf16 hi/lo (zero-pad OOB) ----
    for (int idx = tid; idx < 5280; idx += 256) {
        const int c = idx / 660, rem = idx - c * 660;
        const int row = rem / 66, col = rem - row * 66;
        const int gy = y0t + row - 1, gx = x0 + col - 1;
        float v = 0.0f;
        if (((unsigned)gy < (unsigned)HH) & ((unsigned)gx < (unsigned)WW))
            v = gb[c * HW + gy * WW + gx];
        const unsigned short hi = f2bf(v);
        const unsigned short lo = f2bf(v - bf2f(hi));
        gpk[idx] = ((uint32_t)hi << 16) | lo;
    }
    // ---- stage weight matrix [o(32,pad)][k(96,pad)] fp32, zeros on pad ----
    for (int idx = tid; idx < 3072; idx += 256) {
        const int o = idx / 96, k = idx - o * 96;
        float v = 0.0f;
        if (o < 25 && k < 72) {
            const int c = k / 9, t = k - 9 * c;
            v = (o < 9) ? aw[(o * 8 + c) * 9 + t] : ow[((o - 9) * 8 + c) * 9 + t];
        }
        wst[idx] = v;
    }
    // ---- offtab[s][e][g]: gpk word-offset of (c, dy, dx) for that k ----
    if (tid < 96) {
        const int s = tid >> 5, rem = tid & 31, e = rem >> 2, gq = rem & 3;
        const int k = s * 32 + gq * 8 + e;
        uint32_t off = 0;
        if (k < 72) {
            const int c = k / 9, t = k - 9 * c, dy = t / 3, dx = t - 3 * dy;
            off = (uint32_t)(c * 660 + dy * 66 + dx);
        }
        offtab[tid] = off;
    }
    __syncthreads();

    const int lane = tid & 63, wid = tid >> 6;
    const int grp = lane >> 4, l15 = lane & 15;

    // ---- A fragments: lane supplies A[m = l15][k = s*32 + grp*8 + e] ----
    short8 Ah0[3], Ah1[3], Al0[3], Al1[3];
    {
        const int kb = grp * 8;
#pragma unroll
        for (int s = 0; s < 3; ++s) {
            const float* wp0 = &wst[l15 * 96 + s * 32 + kb];
            const float* wp1 = &wst[(16 + l15) * 96 + s * 32 + kb];
            short8 h0, l0, h1, l1;
#pragma unroll
            for (int e = 0; e < 8; ++e) {
                const float v0 = wp0[e];
                const unsigned short hb0 = f2bf(v0);
                h0[e] = (short)hb0;
                l0[e] = (short)f2bf(v0 - bf2f(hb0));
                const float v1 = wp1[e];
                const unsigned short hb1 = f2bf(v1);
                h1[e] = (short)hb1;
                l1[e] = (short)f2bf(v1 - bf2f(hb1));
            }
            Ah0[s] = h0; Al0[s] = l0; Ah1[s] = h1; Al1[s] = l1;
        }
    }

    // ---- per-lane B-read byte addresses (24) ----
    uint32_t cvaddr[3][8];
#pragma unroll
    for (int s = 0; s < 3; ++s)
#pragma unroll
        for (int e = 0; e < 8; ++e)
            cvaddr[s][e] = (offtab[s * 32 + e * 4 + grp] +
                            (uint32_t)(wid * 132 + l15)) * 4u;

    // ---- uniform epilogue params (s_loads) ----
    float abv[9], w3v[9], obv[16];
#pragma unroll
    for (int t = 0; t < 9; ++t) { abv[t] = ab[t]; w3v[t] = w3[t]; }
#pragma unroll
    for (int o = 0; o < 16; ++o) obv[o] = ob[o];
    const float b3v = b3[0];

    __syncthreads();   // all waves done reading wst before ct reuse

    float* ct = ctb + wid * (64 * CT_STRIDE);
    const float* fb = featPrev + (size_t)b * HW;
    const int ybase = y0t + wid * 2;
    const unsigned char* gpkB = (const unsigned char*)gpk;

#pragma unroll 1
    for (int r = 0; r < 2; ++r) {
        const int y = ybase + r;
        // ---- 4 MFMA chunks back-to-back: conv outputs for the 64-px row ----
#pragma unroll
        for (int ch = 0; ch < 4; ++ch) {
            floatx4 acc0 = {0.f, 0.f, 0.f, 0.f};
            floatx4 acc1 = {0.f, 0.f, 0.f, 0.f};
#pragma unroll
            for (int s = 0; s < 3; ++s) {
                uint32_t ev[8];
#pragma unroll
                for (int e = 0; e < 8; ++e)
                    ev[e] = *(const uint32_t*)(gpkB + cvaddr[s][e] +
                                               (r * 66 + ch * 16) * 4);
                union { uint32_t u[4]; short8 v; } bh, bl;
#pragma unroll
                for (int i = 0; i < 4; ++i) {
                    bh.u[i] = (ev[2 * i] >> 16) | (ev[2 * i + 1] & 0xFFFF0000u);
                    bl.u[i] = (ev[2 * i] & 0xFFFFu) | (ev[2 * i + 1] << 16);
                }
                acc0 = __builtin_amdgcn_mfma_f32_16x16x32_bf16(Ah0[s], bh.v, acc0, 0, 0, 0);
                acc1 = __builtin_amdgcn_mfma_f32_16x16x32_bf16(Ah1[s], bh.v, acc1, 0, 0, 0);
                acc0 = __builtin_amdgcn_mfma_f32_16x16x32_bf16(Ah0[s], bl.v, acc0, 0, 0, 0);
                acc1 = __builtin_amdgcn_mfma_f32_16x16x32_bf16(Ah1[s], bl.v, acc1, 0, 0, 0);
                acc0 = __builtin_amdgcn_mfma_f32_16x16x32_bf16(Al0[s], bh.v, acc0, 0, 0, 0);
                acc1 = __builtin_amdgcn_mfma_f32_16x16x32_bf16(Al1[s], bh.v, acc1, 0, 0, 0);
            }
            // C layout: col(px) = l15, row(o) = grp*4 + i  (+16 for Mtile1)
            const int pxb = (ch * 16 + l15) * CT_STRIDE;
#pragma unroll
            for (int i = 0; i < 4; ++i) {
                ct[pxb + grp * 4 + i] = acc0[i];
                if (grp * 4 + i < 9)                    // only o=16..24 valid
                    ct[pxb + 16 + grp * 4 + i] = acc1[i];
            }
        }

        // ---- epilogue: lane owns pixel x0+lane of row y ----
        const float* cb = ct + lane * CT_STRIDE;
        float av[25];
#pragma unroll
        for (int o = 0; o < 25; ++o) av[o] = cb[o];

        float wg[9], wsum = 1e-8f;
#pragma unroll
        for (int t = 0; t < 9; ++t) {
            const float s = 1.0f / (1.0f + __expf(-(av[t] + abv[t])));
            wg[t] = s;
            wsum += s;
        }
        const float winv = 1.0f / wsum;
        const int x = x0 + lane;

        float sum = 0.0f;
#pragma unroll
        for (int t = 0; t < 9; ++t) {
            float oy, ox;
            if (t < 4)       { oy = av[9 + 2 * t] + obv[2 * t];
                               ox = av[10 + 2 * t] + obv[2 * t + 1]; }
            else if (t == 4) { oy = 0.0f; ox = 0.0f; }
            else             { oy = av[7 + 2 * t] + obv[2 * t - 2];
                               ox = av[8 + 2 * t] + obv[2 * t - 1]; }

            const float py = (float)(y - 1 + (t / 3)) + oy;
            const float px = (float)(x - 1 + (t % 3)) + ox;
            const float fy = floorf(py), fx = floorf(px);
            const float wy = py - fy, wx = px - fx;
            const int iy = (int)fy, ix = (int)fx;
            const int iy1 = iy + 1, ix1 = ix + 1;

            const int ry0 = min(max(iy, 0), HH - 1) * WW;
            const int ry1 = min(max(iy1, 0), HH - 1) * WW;
            const int cx0 = min(max(ix, 0), WW - 1);
            const int cx1 = min(max(ix1, 0), WW - 1);
            const float v00 = fb[ry0 + cx0], v01 = fb[ry0 + cx1];
            const float v10 = fb[ry1 + cx0], v11 = fb[ry1 + cx1];

            const bool vy0 = (unsigned)iy < (unsigned)HH;
            const bool vy1 = (unsigned)iy1 < (unsigned)HH;
            const bool vx0 = (unsigned)ix < (unsigned)WW;
            const bool vx1 = (unsigned)ix1 < (unsigned)WW;
            const float wy0 = 1.0f - wy, wx0 = 1.0f - wx;

            float s = 0.0f;
            s = fmaf((vy0 & vx0) ? wy0 * wx0 : 0.0f, v00, s);
            s = fmaf((vy0 & vx1) ? wy0 * wx  : 0.0f, v01, s);
            s = fmaf((vy1 & vx0) ? wy  * wx0 : 0.0f, v10, s);
            s = fmaf((vy1 & vx1) ? wy  * wx  : 0.0f, v11, s);

            sum = fmaf(wg[t] * w3v[t], s, sum);
        }
        featNext[(size_t)b * HW + (size_t)y * WW + x] = fmaf(winv, sum, b3v);
    }
}

// ---------------------------------------------------------------------------
// Stage 1 of BN stats: per-block partial sums (float4-vectorized).
// ---------------------------------------------------------------------------
__global__ __launch_bounds__(256) void stats_part(
    const float* __restrict__ y0s, const float* __restrict__ y1s,
    const float* __restrict__ y2s, float* __restrict__ part)
{
    float a[9] = {0, 0, 0, 0, 0, 0, 0, 0, 0};
    const int n4 = NPIX / 4;
    const int stride = gridDim.x * 256;
    for (int i = blockIdx.x * 256 + threadIdx.x; i < n4; i += stride) {
        const float4 q0 = ((const float4*)y0s)[i];
        const float4 q1 = ((const float4*)y1s)[i];
        const float4 q2 = ((const float4*)y2s)[i];
        const float v0s[4] = {q0.x, q0.y, q0.z, q0.w};
        const float v1s[4] = {q1.x, q1.y, q1.z, q1.w};
        const float v2s[4] = {q2.x, q2.y, q2.z, q2.w};
#pragma unroll
        for (int j = 0; j < 4; ++j) {
            const float v0 = v0s[j], v1 = v1s[j], v2 = v2s[j];
            a[0] += v0; a[1] += v1; a[2] += v2;
            a[3] = fmaf(v0, v0, a[3]); a[4] = fmaf(v0, v1, a[4]);
            a[5] = fmaf(v0, v2, a[5]); a[6] = fmaf(v1, v1, a[6]);
            a[7] = fmaf(v1, v2, a[7]); a[8] = fmaf(v2, v2, a[8]);
        }
    }
    __shared__ float red[4][9];
    const int lane = threadIdx.x & 63, wv = threadIdx.x >> 6;
#pragma unroll
    for (int q = 0; q < 9; ++q) {
        float v = a[q];
        for (int o = 32; o; o >>= 1) v += __shfl_down(v, o, 64);
        if (lane == 0) red[wv][q] = v;
    }
    __syncthreads();
    if (threadIdx.x < 9) {
        const int q = threadIdx.x;
        part[blockIdx.x * 9 + q] = red[0][q] + red[1][q] + red[2][q] + red[3][q];
    }
}

// ---------------------------------------------------------------------------
// Stage 2: finalize per-channel BN scale/shift for sf = proj(y).
// ---------------------------------------------------------------------------
__global__ __launch_bounds__(256) void stats_final(
    const float* __restrict__ part, const float* __restrict__ proj_w,
    const float* __restrict__ bn_g, const float* __restrict__ bn_b,
    float* __restrict__ stats)
{
    float a[9] = {0, 0, 0, 0, 0, 0, 0, 0, 0};
    for (int i = threadIdx.x; i < NPART; i += 256) {
#pragma unroll
        for (int q = 0; q < 9; ++q) a[q] += part[i * 9 + q];
    }
    __shared__ float red[4][9];
    const int lane = threadIdx.x & 63, wv = threadIdx.x >> 6;
#pragma unroll
    for (int q = 0; q < 9; ++q) {
        float v = a[q];
        for (int o = 32; o; o >>= 1) v += __shfl_down(v, o, 64);
        if (lane == 0) red[wv][q] = v;
    }
    __syncthreads();
    if (threadIdx.x == 0) {
        float s[9];
#pragma unroll
        for (int q = 0; q < 9; ++q) s[q] = red[0][q] + red[1][q] + red[2][q] + red[3][q];
        const float invN = 1.0f / (float)NPIX;
        const float m0 = s[0] * invN, m1 = s[1] * invN, m2 = s[2] * invN;
        const float E00 = s[3] * invN, E01 = s[4] * invN, E02 = s[5] * invN;
        const float E11 = s[6] * invN, E12 = s[7] * invN, E22 = s[8] * invN;
#pragma unroll
        for (int c = 0; c < 6; ++c) {
            const float p0 = proj_w[c * 3], p1 = proj_w[c * 3 + 1], p2 = proj_w[c * 3 + 2];
            const float mu = p0 * m0 + p1 * m1 + p2 * m2;
            const float e2 = p0 * p0 * E00 + p1 * p1 * E11 + p2 * p2 * E22 +
                             2.0f * (p0 * p1 * E01 + p0 * p2 * E02 + p1 * p2 * E12);
            const float var = e2 - mu * mu;
            const float sc = bn_g[c] / sqrtf(var + 1e-5f);
            stats[c] = sc;
            stats[6 + c] = bn_b[c] - mu * sc;
        }
    }
}

// ---------------------------------------------------------------------------
// Fused head, tile 32x8. Phase 1 float4-vectorized (job = channel x row x
// 4-px chunk); XCD-swizzled 1D grid; a1/a2 in registers.
// ---------------------------------------------------------------------------
constexpr int HB_X = WW / 32;          // 38
constexpr int HB_Y = HH / 8;           // 30
constexpr int HB_N = HB_X * HB_Y * BATCH;   // 4560 (divisible by 8)
constexpr int HB_CHUNK = HB_N / 8;     // 570

__global__ __launch_bounds__(256, 4) void head_kernel(
    const float* __restrict__ y0s, const float* __restrict__ y1s,
    const float* __restrict__ y2s, const float* __restrict__ attn,
    const float* __restrict__ stats,   // scale[6], shift[6]
    const float* __restrict__ proj_w,
    const float* __restrict__ c0_w, const float* __restrict__ c0_b,
    const float* __restrict__ cs_w, const float* __restrict__ cs_b,
    const float* __restrict__ c1_w, const float* __restrict__ c1_b,
    const float* __restrict__ c2_w, const float* __restrict__ c2_b,
    const float* __restrict__ csq_w, const float* __restrict__ csq_b,
    const float* __restrict__ cv_w, const float* __restrict__ cv_b,
    float* __restrict__ out)
{
    __shared__ float ap[22][432];    // a1_pre, ext tile 12x36 (halo 2)
    __shared__ float aggs[2][340];   // agg, tile+halo1 10x34

    const int tid = threadIdx.x;
    // XCD-aware bijective swizzle: 8 XCDs x 570 contiguous tiles
    const int bid = blockIdx.x;
    const int swz = (bid & 7) * HB_CHUNK + (bid >> 3);
    const int b = swz / (HB_X * HB_Y);
    const int rem0 = swz - b * (HB_X * HB_Y);
    const int by = rem0 / HB_X;
    const int bx = rem0 - by * HB_X;
    const int x0 = bx * 32;
    const int y0t = by * 8;

    // ---- phase 1: a1_pre over ext tile, float4 jobs ----
    // attn jobs: 16c x 12r x 10xc = 1920 ; y jobs: 12r x 10xc = 120
    for (int job = tid; job < 2040; job += 256) {
        int c = 0, rr, xc;
        bool isY;
        if (job < 1920) {
            c = job / 120;
            const int rem = job - c * 120;
            rr = rem / 10; xc = rem - rr * 10;
            isY = false;
        } else {
            const int rem = job - 1920;
            rr = rem / 10; xc = rem - rr * 10;
            isY = true;
        }
        const int gy = y0t + rr - 2;
        const int gxb = x0 - 4 + 4 * xc;           // 16B-aligned
        const bool gok = ((unsigned)gy < (unsigned)HH) &
                         ((unsigned)gxb <= (unsigned)(WW - 4));
        const size_t prow = (size_t)gy * WW + gxb;

        if (!isY) {
            float4 v4 = {0.f, 0.f, 0.f, 0.f};
            if (gok)
                v4 = *(const float4*)&attn[(size_t)b * 16 * HW + (size_t)c * HW + prow];
            const float w = c0_w[c], bb = c0_b[c];
            const float vin[4] = {v4.x, v4.y, v4.z, v4.w};
#pragma unroll
            for (int j = 0; j < 4; ++j) {
                const int exl = 4 * xc - 2 + j;
                if ((unsigned)exl < 36u)
                    ap[c][rr * 36 + exl] = gok ? fmaf(w, vin[j], bb) : 0.0f;
            }
        } else {
            float4 q0 = {0.f, 0.f, 0.f, 0.f}, q1 = q0, q2 = q0;
            if (gok) {
                const size_t p = (size_t)b * HW + prow;
                q0 = *(const float4*)&y0s[p];
                q1 = *(const float4*)&y1s[p];
                q2 = *(const float4*)&y2s[p];
            }
            const float v0s[4] = {q0.x, q0.y, q0.z, q0.w};
            const float v1s[4] = {q1.x, q1.y, q1.z, q1.w};
            const float v2s[4] = {q2.x, q2.y, q2.z, q2.w};
#pragma unroll
            for (int j = 0; j < 4; ++j) {
                const int exl = 4 * xc - 2 + j;
                if ((unsigned)exl >= 36u) continue;
#pragma unroll
                for (int q = 0; q < 6; ++q) {
                    float v = 0.0f;
                    if (gok) {
                        const float sraw = proj_w[q * 3] * v0s[j] +
                                           proj_w[q * 3 + 1] * v1s[j] +
                                           proj_w[q * 3 + 2] * v2s[j];
                        float sf = fmaf(stats[q], sraw, stats[6 + q]);
                        sf = sf > 0.0f ? sf : 0.2f * sf;
                        v = fmaf(c0_w[16 + q], sf, c0_b[16 + q]);
                    }
                    ap[16 + q][rr * 36 + exl] = v;
                }
            }
        }
    }
    __syncthreads();

    // computes a1[11], a2[11] at agg coords (ay,ax)
    auto compute_px = [&](int ay, int ax, float* a1, float* a2) {
        const int ey = ay + 1, ex = ax + 1;   // ext coords
#pragma unroll
        for (int j = 0; j < 11; ++j) { a1[j] = c1_b[j]; a2[j] = c2_b[j]; }
#pragma unroll
        for (int c = 0; c < 22; ++c) {
            float dw = cs_b[c];
            float ctr = 0.0f;
#pragma unroll
            for (int t = 0; t < 9; ++t) {
                const float av = ap[c][(ey + t / 3 - 1) * 36 + (ex + t % 3 - 1)];
                dw = fmaf(cs_w[c * 9 + t], av, dw);
                if (t == 4) ctr = av;
            }
#pragma unroll
            for (int j = 0; j < 11; ++j) {
                a1[j] = fmaf(c1_w[j * 22 + c], ctr, a1[j]);
                a2[j] = fmaf(c2_w[j * 22 + c], dw, a2[j]);
            }
        }
    };

    // ---- phase 2a: ring jobs (84 halo pixels of the 10x34 agg region) ----
    if (tid < 84) {
        int ay, ax;
        if (tid < 34)      { ay = 0; ax = tid; }
        else if (tid < 68) { ay = 9; ax = tid - 34; }
        else { const int s = tid - 68; ay = 1 + (s >> 1); ax = (s & 1) ? 33 : 0; }
        const int gy = y0t + ay - 1, gx = x0 + ax - 1;
        float m0 = 0.0f, m1 = 0.0f;
        if (((unsigned)gy < (unsigned)HH) & ((unsigned)gx < (unsigned)WW)) {
            float a1h[11], a2h[11];
            compute_px(ay, ax, a1h, a2h);
            float s = 0.0f, mx = -INFINITY;
#pragma unroll
            for (int j = 0; j < 11; ++j) {
                s += a1h[j] + a2h[j];
                mx = fmaxf(mx, fmaxf(a1h[j], a2h[j]));
            }
            m0 = s * (1.0f / 22.0f);
            m1 = mx;
        }
        aggs[0][ay * 34 + ax] = m0;
        aggs[1][ay * 34 + ax] = m1;
    }

    // ---- phase 2b: center pixel, keep a1/a2 in registers ----
    const int ty = tid >> 5, tx = tid & 31;
    const int ay = ty + 1, ax = tx + 1;
    float a1[11], a2[11];
    compute_px(ay, ax, a1, a2);
    {
        float s = 0.0f, mx = -INFINITY;
#pragma unroll
        for (int j = 0; j < 11; ++j) {
            s += a1[j] + a2[j];
            mx = fmaxf(mx, fmaxf(a1[j], a2[j]));
        }
        aggs[0][ay * 34 + ax] = s * (1.0f / 22.0f);
        aggs[1][ay * 34 + ax] = mx;
    }
    __syncthreads();

    // ---- phase 3: sigmoid gate + cv + final dot with y ----
    float z0 = csq_b[0], z1 = csq_b[1];
#pragma unroll
    for (int t = 0; t < 9; ++t) {
        const int ai = (ay + t / 3 - 1) * 34 + (ax + t % 3 - 1);
        const float g0 = aggs[0][ai], g1 = aggs[1][ai];
        z0 = fmaf(csq_w[t], g0, fmaf(csq_w[9 + t], g1, z0));
        z1 = fmaf(csq_w[18 + t], g0, fmaf(csq_w[27 + t], g1, z1));
    }
    const float s0 = 1.0f / (1.0f + __expf(-z0));
    const float s1 = 1.0f / (1.0f + __expf(-z1));
    float v0 = cv_b[0], v1 = cv_b[1], v2 = cv_b[2];
#pragma unroll
    for (int j = 0; j < 11; ++j) {
        const float av = a1[j] * s0 + a2[j] * s1;
        v0 = fmaf(cv_w[j], av, v0);
        v1 = fmaf(cv_w[11 + j], av, v1);
        v2 = fmaf(cv_w[22 + j], av, v2);
    }
    const size_t p = (size_t)b * HW + (size_t)(y0t + ty) * WW + (x0 + tx);
    out[p] = y0s[p] * v0 + y1s[p] * v1 + y2s[p] * v2;
}

// ---------------------------------------------------------------------------
extern "C" void kernel_launch(void* const* d_in, const int* in_sizes, int n_in,
                              void* d_out, int out_size, void* d_ws, size_t ws_size,
                              hipStream_t stream)
{
    (void)in_sizes; (void)n_in; (void)out_size; (void)ws_size;
    const float* feat_init = (const float*)d_in[0];
    const float* guidance  = (const float*)d_in[1];
    const float* attn      = (const float*)d_in[2];
    const float* aff_w_w   = (const float*)d_in[4];
    const float* aff_w_b   = (const float*)d_in[5];
    const float* aff_o_w   = (const float*)d_in[6];
    const float* aff_o_b   = (const float*)d_in[7];
    const float* w3        = (const float*)d_in[8];
    const float* b3        = (const float*)d_in[9];
    const float* proj_w    = (const float*)d_in[10];
    const float* bn_g      = (const float*)d_in[11];
    const float* bn_b      = (const float*)d_in[12];
    const float* c0_w      = (const float*)d_in[13];
    const float* c0_b      = (const float*)d_in[14];
    const float* cs_w      = (const float*)d_in[15];
    const float* cs_b      = (const float*)d_in[16];
    const float* c1_w      = (const float*)d_in[17];
    const float* c1_b      = (const float*)d_in[18];
    const float* c2_w      = (const float*)d_in[19];
    const float* c2_b      = (const float*)d_in[20];
    const float* csq_w     = (const float*)d_in[21];
    const float* csq_b     = (const float*)d_in[22];
    const float* cv_w      = (const float*)d_in[23];
    const float* cv_b      = (const float*)d_in[24];

    float* ws = (float*)d_ws;
    float* slot[5];
    for (int i = 0; i < 5; ++i) slot[i] = ws + (size_t)i * NPIX;
    float* part  = ws + (size_t)5 * NPIX;
    float* stats = part + (size_t)9 * NPART;

    const dim3 blk(256);
    const dim3 gp(WW / 64, HH / 8, BATCH);

    // propagation chain; keep feats[3],[4],[5] in slots 2,3,4
    const int dst_ids[PROP] = {0, 1, 0, 2, 3, 4};
    const float* src = feat_init;
    for (int k = 0; k < PROP; ++k) {
        float* dst = slot[dst_ids[k]];
        prop_kernel<<<gp, blk, 0, stream>>>(
            src, guidance + (size_t)8 * k * HW,
            aff_w_w + (size_t)k * 648, aff_w_b + (size_t)k * 9,
            aff_o_w + (size_t)k * 1152, aff_o_b + (size_t)k * 16,
            w3, b3, dst);
        src = dst;
    }

    stats_part<<<dim3(NPART), blk, 0, stream>>>(slot[2], slot[3], slot[4], part);
    stats_final<<<dim3(1), blk, 0, stream>>>(part, proj_w, bn_g, bn_b, stats);

    head_kernel<<<dim3(HB_N), blk, 0, stream>>>(
        slot[2], slot[3], slot[4], attn, stats, proj_w,
        c0_w, c0_b, cs_w, cs_b, c1_w, c1_b, c2_w, c2_b,
        csq_w, csq_b, cv_w, cv_b, (float*)d_out);
}

// Round 7
// 598.409 us; speedup vs baseline: 1.7406x; 1.0467x over previous
//
#include <hip/hip_runtime.h>
#include <hip/hip_bf16.h>
#include <math.h>

#define HH 240
#define WW 1216
#define BATCH 4
#define PROP 6
constexpr int HW = HH * WW;            // 291,840
constexpr int NPIX = BATCH * HW;       // 1,167,360
constexpr int NPART = 1024;

typedef short short8 __attribute__((ext_vector_type(8)));
typedef float floatx4 __attribute__((ext_vector_type(4)));

__device__ __forceinline__ unsigned short f2bf(float f) {
    unsigned int u = __float_as_uint(f);
    unsigned int r = (u + 0x7FFFu + ((u >> 16) & 1u)) >> 16;
    return (unsigned short)r;
}
__device__ __forceinline__ float bf2f(unsigned short h) {
    return __uint_as_float(((unsigned int)h) << 16);
}

// LDS layout (bytes):
//   gs16   [8][10][66] u16 (bf16-hi guidance)      @ 0      : 10560
//   offtab [3][8][4]   u32                          @ 10560  : 384
//   region2 @ 10944: wst [32][96] f32 (12288, dead after A-build)
//                    | ct 4 waves x [64][26] f32 (26624)
constexpr int CT_STRIDE = 26;          // gcd(26,32)=2 -> free 2-way aliasing
constexpr int SMEM_BYTES = 10944 + 4 * 64 * CT_STRIDE * 4;   // 37568 -> 4 blk/CU

// ---------------------------------------------------------------------------
// Propagation v6: affinity conv (25x72) on MFMA. Guidance bf16-hi only
// (B-side), weights hi/lo 2-term (A-side). Lane-owns-pixel epilogue.
// ---------------------------------------------------------------------------
__global__ __launch_bounds__(256, 4) void prop_kernel(
    const float* __restrict__ featPrev,   // [B][HW]
    const float* __restrict__ gbase,      // guidance + 8k*HW; batch stride 48*HW
    const float* __restrict__ aw,         // [9][8][3][3]
    const float* __restrict__ ab,         // [9]
    const float* __restrict__ ow,         // [16][8][3][3]
    const float* __restrict__ ob,         // [16]
    const float* __restrict__ w3,         // [9]
    const float* __restrict__ b3,         // [1]
    float* __restrict__ featNext)         // [B][HW]
{
    __shared__ __attribute__((aligned(16))) unsigned char smem[SMEM_BYTES];
    unsigned short* gs16 = (unsigned short*)smem;
    uint32_t* offtab = (uint32_t*)(smem + 10560);
    float*    wst    = (float*)(smem + 10944);
    float*    ctb    = (float*)(smem + 10944);

    const int tid = threadIdx.x;
    const int x0 = blockIdx.x * 64;
    const int y0t = blockIdx.y * 8;
    const int b = blockIdx.z;
    const float* gb = gbase + (size_t)b * (48 * HW);

    // ---- stage guidance ext tile as bf16-hi u16 (zero-pad OOB) ----
    for (int idx = tid; idx < 5280; idx += 256) {
        const int c = idx / 660, rem = idx - c * 660;
        const int row = rem / 66, col = rem - row * 66;
        const int gy = y0t + row - 1, gx = x0 + col - 1;
        float v = 0.0f;
        if (((unsigned)gy < (unsigned)HH) & ((unsigned)gx < (unsigned)WW))
            v = gb[c * HW + gy * WW + gx];
        gs16[idx] = f2bf(v);
    }
    // ---- stage weight matrix [o(32,pad)][k(96,pad)] fp32, zeros on pad ----
    for (int idx = tid; idx < 3072; idx += 256) {
        const int o = idx / 96, k = idx - o * 96;
        float v = 0.0f;
        if (o < 25 && k < 72) {
            const int c = k / 9, t = k - 9 * c;
            v = (o < 9) ? aw[(o * 8 + c) * 9 + t] : ow[((o - 9) * 8 + c) * 9 + t];
        }
        wst[idx] = v;
    }
    // ---- offtab[s][e][g]: gs16 element-offset of (c, dy, dx) for that k ----
    if (tid < 96) {
        const int s = tid >> 5, rem = tid & 31, e = rem >> 2, gq = rem & 3;
        const int k = s * 32 + gq * 8 + e;
        uint32_t off = 0;
        if (k < 72) {
            const int c = k / 9, t = k - 9 * c, dy = t / 3, dx = t - 3 * dy;
            off = (uint32_t)(c * 660 + dy * 66 + dx);
        }
        offtab[tid] = off;
    }
    __syncthreads();

    const int lane = tid & 63, wid = tid >> 6;
    const int grp = lane >> 4, l15 = lane & 15;

    // ---- A fragments: lane supplies A[m = l15][k = s*32 + grp*8 + e] ----
    short8 Ah0[3], Ah1[3], Al0[3], Al1[3];
    {
        const int kb = grp * 8;
#pragma unroll
        for (int s = 0; s < 3; ++s) {
            const float* wp0 = &wst[l15 * 96 + s * 32 + kb];
            const float* wp1 = &wst[(16 + l15) * 96 + s * 32 + kb];
            short8 h0, l0, h1, l1;
#pragma unroll
            for (int e = 0; e < 8; ++e) {
                const float v0 = wp0[e];
                const unsigned short hb0 = f2bf(v0);
                h0[e] = (short)hb0;
                l0[e] = (short)f2bf(v0 - bf2f(hb0));
                const float v1 = wp1[e];
                const unsigned short hb1 = f2bf(v1);
                h1[e] = (short)hb1;
                l1[e] = (short)f2bf(v1 - bf2f(hb1));
            }
            Ah0[s] = h0; Al0[s] = l0; Ah1[s] = h1; Al1[s] = l1;
        }
    }

    // ---- per-lane B-read byte addresses (24) ----
    uint32_t cvaddr[3][8];
#pragma unroll
    for (int s = 0; s < 3; ++s)
#pragma unroll
        for (int e = 0; e < 8; ++e)
            cvaddr[s][e] = (offtab[s * 32 + e * 4 + grp] +
                            (uint32_t)(wid * 132 + l15)) * 2u;

    // ---- uniform epilogue params (s_loads) ----
    float abv[9], w3v[9], obv[16];
#pragma unroll
    for (int t = 0; t < 9; ++t) { abv[t] = ab[t]; w3v[t] = w3[t]; }
#pragma unroll
    for (int o = 0; o < 16; ++o) obv[o] = ob[o];
    const float b3v = b3[0];

    __syncthreads();   // all waves done reading wst before ct reuse

    float* ct = ctb + wid * (64 * CT_STRIDE);
    const float* fb = featPrev + (size_t)b * HW;
    const int ybase = y0t + wid * 2;
    const unsigned char* gsB = (const unsigned char*)gs16;

#pragma unroll 1
    for (int r = 0; r < 2; ++r) {
        const int y = ybase + r;
        // ---- 4 MFMA chunks back-to-back: conv outputs for the 64-px row ----
#pragma unroll
        for (int ch = 0; ch < 4; ++ch) {
            floatx4 acc0 = {0.f, 0.f, 0.f, 0.f};
            floatx4 acc1 = {0.f, 0.f, 0.f, 0.f};
#pragma unroll
            for (int s = 0; s < 3; ++s) {
                uint32_t ev[8];
#pragma unroll
                for (int e = 0; e < 8; ++e)
                    ev[e] = *(const unsigned short*)(gsB + cvaddr[s][e] +
                                                     (r * 66 + ch * 16) * 2);
                union { uint32_t u[4]; short8 v; } bh;
#pragma unroll
                for (int i = 0; i < 4; ++i)
                    bh.u[i] = ev[2 * i] | (ev[2 * i + 1] << 16);
                acc0 = __builtin_amdgcn_mfma_f32_16x16x32_bf16(Ah0[s], bh.v, acc0, 0, 0, 0);
                acc1 = __builtin_amdgcn_mfma_f32_16x16x32_bf16(Ah1[s], bh.v, acc1, 0, 0, 0);
                acc0 = __builtin_amdgcn_mfma_f32_16x16x32_bf16(Al0[s], bh.v, acc0, 0, 0, 0);
                acc1 = __builtin_amdgcn_mfma_f32_16x16x32_bf16(Al1[s], bh.v, acc1, 0, 0, 0);
            }
            // C layout: col(px) = l15, row(o) = grp*4 + i  (+16 for Mtile1)
            const int pxb = (ch * 16 + l15) * CT_STRIDE;
#pragma unroll
            for (int i = 0; i < 4; ++i) {
                ct[pxb + grp * 4 + i] = acc0[i];
                if (grp * 4 + i < 9)                    // only o=16..24 valid
                    ct[pxb + 16 + grp * 4 + i] = acc1[i];
            }
        }

        // ---- epilogue: lane owns pixel x0+lane of row y ----
        const float* cb = ct + lane * CT_STRIDE;
        float av[25];
#pragma unroll
        for (int o = 0; o < 25; ++o) av[o] = cb[o];

        float wg[9], wsum = 1e-8f;
#pragma unroll
        for (int t = 0; t < 9; ++t) {
            const float s = 1.0f / (1.0f + __expf(-(av[t] + abv[t])));
            wg[t] = s;
            wsum += s;
        }
        const float winv = 1.0f / wsum;
        const int x = x0 + lane;

        float sum = 0.0f;
#pragma unroll
        for (int t = 0; t < 9; ++t) {
            float oy, ox;
            if (t < 4)       { oy = av[9 + 2 * t] + obv[2 * t];
                               ox = av[10 + 2 * t] + obv[2 * t + 1]; }
            else if (t == 4) { oy = 0.0f; ox = 0.0f; }
            else             { oy = av[7 + 2 * t] + obv[2 * t - 2];
                               ox = av[8 + 2 * t] + obv[2 * t - 1]; }

            const float py = (float)(y - 1 + (t / 3)) + oy;
            const float px = (float)(x - 1 + (t % 3)) + ox;
            const float fy = floorf(py), fx = floorf(px);
            const float wy = py - fy, wx = px - fx;
            const int iy = (int)fy, ix = (int)fx;
            const int iy1 = iy + 1, ix1 = ix + 1;

            const int ry0 = min(max(iy, 0), HH - 1) * WW;
            const int ry1 = min(max(iy1, 0), HH - 1) * WW;
            const int cx0 = min(max(ix, 0), WW - 1);
            const int cx1 = min(max(ix1, 0), WW - 1);
            const float v00 = fb[ry0 + cx0], v01 = fb[ry0 + cx1];
            const float v10 = fb[ry1 + cx0], v11 = fb[ry1 + cx1];

            const bool vy0 = (unsigned)iy < (unsigned)HH;
            const bool vy1 = (unsigned)iy1 < (unsigned)HH;
            const bool vx0 = (unsigned)ix < (unsigned)WW;
            const bool vx1 = (unsigned)ix1 < (unsigned)WW;
            const float wy0 = 1.0f - wy, wx0 = 1.0f - wx;

            float s = 0.0f;
            s = fmaf((vy0 & vx0) ? wy0 * wx0 : 0.0f, v00, s);
            s = fmaf((vy0 & vx1) ? wy0 * wx  : 0.0f, v01, s);
            s = fmaf((vy1 & vx0) ? wy  * wx0 : 0.0f, v10, s);
            s = fmaf((vy1 & vx1) ? wy  * wx  : 0.0f, v11, s);

            sum = fmaf(wg[t] * w3v[t], s, sum);
        }
        featNext[(size_t)b * HW + (size_t)y * WW + x] = fmaf(winv, sum, b3v);
    }
}

// ---------------------------------------------------------------------------
// Stage 1 of BN stats: per-block partial sums (float4-vectorized).
// ---------------------------------------------------------------------------
__global__ __launch_bounds__(256) void stats_part(
    const float* __restrict__ y0s, const float* __restrict__ y1s,
    const float* __restrict__ y2s, float* __restrict__ part)
{
    float a[9] = {0, 0, 0, 0, 0, 0, 0, 0, 0};
    const int n4 = NPIX / 4;
    const int stride = gridDim.x * 256;
    for (int i = blockIdx.x * 256 + threadIdx.x; i < n4; i += stride) {
        const float4 q0 = ((const float4*)y0s)[i];
        const float4 q1 = ((const float4*)y1s)[i];
        const float4 q2 = ((const float4*)y2s)[i];
        const float v0s[4] = {q0.x, q0.y, q0.z, q0.w};
        const float v1s[4] = {q1.x, q1.y, q1.z, q1.w};
        const float v2s[4] = {q2.x, q2.y, q2.z, q2.w};
#pragma unroll
        for (int j = 0; j < 4; ++j) {
            const float v0 = v0s[j], v1 = v1s[j], v2 = v2s[j];
            a[0] += v0; a[1] += v1; a[2] += v2;
            a[3] = fmaf(v0, v0, a[3]); a[4] = fmaf(v0, v1, a[4]);
            a[5] = fmaf(v0, v2, a[5]); a[6] = fmaf(v1, v1, a[6]);
            a[7] = fmaf(v1, v2, a[7]); a[8] = fmaf(v2, v2, a[8]);
        }
    }
    __shared__ float red[4][9];
    const int lane = threadIdx.x & 63, wv = threadIdx.x >> 6;
#pragma unroll
    for (int q = 0; q < 9; ++q) {
        float v = a[q];
        for (int o = 32; o; o >>= 1) v += __shfl_down(v, o, 64);
        if (lane == 0) red[wv][q] = v;
    }
    __syncthreads();
    if (threadIdx.x < 9) {
        const int q = threadIdx.x;
        part[blockIdx.x * 9 + q] = red[0][q] + red[1][q] + red[2][q] + red[3][q];
    }
}

// ---------------------------------------------------------------------------
// Stage 2: finalize per-channel BN scale/shift for sf = proj(y).
// ---------------------------------------------------------------------------
__global__ __launch_bounds__(256) void stats_final(
    const float* __restrict__ part, const float* __restrict__ proj_w,
    const float* __restrict__ bn_g, const float* __restrict__ bn_b,
    float* __restrict__ stats)
{
    float a[9] = {0, 0, 0, 0, 0, 0, 0, 0, 0};
    for (int i = threadIdx.x; i < NPART; i += 256) {
#pragma unroll
        for (int q = 0; q < 9; ++q) a[q] += part[i * 9 + q];
    }
    __shared__ float red[4][9];
    const int lane = threadIdx.x & 63, wv = threadIdx.x >> 6;
#pragma unroll
    for (int q = 0; q < 9; ++q) {
        float v = a[q];
        for (int o = 32; o; o >>= 1) v += __shfl_down(v, o, 64);
        if (lane == 0) red[wv][q] = v;
    }
    __syncthreads();
    if (threadIdx.x == 0) {
        float s[9];
#pragma unroll
        for (int q = 0; q < 9; ++q) s[q] = red[0][q] + red[1][q] + red[2][q] + red[3][q];
        const float invN = 1.0f / (float)NPIX;
        const float m0 = s[0] * invN, m1 = s[1] * invN, m2 = s[2] * invN;
        const float E00 = s[3] * invN, E01 = s[4] * invN, E02 = s[5] * invN;
        const float E11 = s[6] * invN, E12 = s[7] * invN, E22 = s[8] * invN;
#pragma unroll
        for (int c = 0; c < 6; ++c) {
            const float p0 = proj_w[c * 3], p1 = proj_w[c * 3 + 1], p2 = proj_w[c * 3 + 2];
            const float mu = p0 * m0 + p1 * m1 + p2 * m2;
            const float e2 = p0 * p0 * E00 + p1 * p1 * E11 + p2 * p2 * E22 +
                             2.0f * (p0 * p1 * E01 + p0 * p2 * E02 + p1 * p2 * E12);
            const float var = e2 - mu * mu;
            const float sc = bn_g[c] / sqrtf(var + 1e-5f);
            stats[c] = sc;
            stats[6 + c] = bn_b[c] - mu * sc;
        }
    }
}

// ---------------------------------------------------------------------------
// Fused head (unchanged from round 5): float4 phase-1, XCD-swizzled grid,
// a1/a2 in registers.
// ---------------------------------------------------------------------------
constexpr int HB_X = WW / 32;          // 38
constexpr int HB_Y = HH / 8;           // 30
constexpr int HB_N = HB_X * HB_Y * BATCH;   // 4560 (divisible by 8)
constexpr int HB_CHUNK = HB_N / 8;     // 570

__global__ __launch_bounds__(256, 4) void head_kernel(
    const float* __restrict__ y0s, const float* __restrict__ y1s,
    const float* __restrict__ y2s, const float* __restrict__ attn,
    const float* __restrict__ stats,   // scale[6], shift[6]
    const float* __restrict__ proj_w,
    const float* __restrict__ c0_w, const float* __restrict__ c0_b,
    const float* __restrict__ cs_w, const float* __restrict__ cs_b,
    const float* __restrict__ c1_w, const float* __restrict__ c1_b,
    const float* __restrict__ c2_w, const float* __restrict__ c2_b,
    const float* __restrict__ csq_w, const float* __restrict__ csq_b,
    const float* __restrict__ cv_w, const float* __restrict__ cv_b,
    float* __restrict__ out)
{
    __shared__ float ap[22][432];    // a1_pre, ext tile 12x36 (halo 2)
    __shared__ float aggs[2][340];   // agg, tile+halo1 10x34

    const int tid = threadIdx.x;
    const int bid = blockIdx.x;
    const int swz = (bid & 7) * HB_CHUNK + (bid >> 3);
    const int b = swz / (HB_X * HB_Y);
    const int rem0 = swz - b * (HB_X * HB_Y);
    const int by = rem0 / HB_X;
    const int bx = rem0 - by * HB_X;
    const int x0 = bx * 32;
    const int y0t = by * 8;

    // ---- phase 1: a1_pre over ext tile, float4 jobs ----
    for (int job = tid; job < 2040; job += 256) {
        int c = 0, rr, xc;
        bool isY;
        if (job < 1920) {
            c = job / 120;
            const int rem = job - c * 120;
            rr = rem / 10; xc = rem - rr * 10;
            isY = false;
        } else {
            const int rem = job - 1920;
            rr = rem / 10; xc = rem - rr * 10;
            isY = true;
        }
        const int gy = y0t + rr - 2;
        const int gxb = x0 - 4 + 4 * xc;           // 16B-aligned
        const bool gok = ((unsigned)gy < (unsigned)HH) &
                         ((unsigned)gxb <= (unsigned)(WW - 4));
        const size_t prow = (size_t)gy * WW + gxb;

        if (!isY) {
            float4 v4 = {0.f, 0.f, 0.f, 0.f};
            if (gok)
                v4 = *(const float4*)&attn[(size_t)b * 16 * HW + (size_t)c * HW + prow];
            const float w = c0_w[c], bb = c0_b[c];
            const float vin[4] = {v4.x, v4.y, v4.z, v4.w};
#pragma unroll
            for (int j = 0; j < 4; ++j) {
                const int exl = 4 * xc - 2 + j;
                if ((unsigned)exl < 36u)
                    ap[c][rr * 36 + exl] = gok ? fmaf(w, vin[j], bb) : 0.0f;
            }
        } else {
            float4 q0 = {0.f, 0.f, 0.f, 0.f}, q1 = q0, q2 = q0;
            if (gok) {
                const size_t p = (size_t)b * HW + prow;
                q0 = *(const float4*)&y0s[p];
                q1 = *(const float4*)&y1s[p];
                q2 = *(const float4*)&y2s[p];
            }
            const float v0s[4] = {q0.x, q0.y, q0.z, q0.w};
            const float v1s[4] = {q1.x, q1.y, q1.z, q1.w};
            const float v2s[4] = {q2.x, q2.y, q2.z, q2.w};
#pragma unroll
            for (int j = 0; j < 4; ++j) {
                const int exl = 4 * xc - 2 + j;
                if ((unsigned)exl >= 36u) continue;
#pragma unroll
                for (int q = 0; q < 6; ++q) {
                    float v = 0.0f;
                    if (gok) {
                        const float sraw = proj_w[q * 3] * v0s[j] +
                                           proj_w[q * 3 + 1] * v1s[j] +
                                           proj_w[q * 3 + 2] * v2s[j];
                        float sf = fmaf(stats[q], sraw, stats[6 + q]);
                        sf = sf > 0.0f ? sf : 0.2f * sf;
                        v = fmaf(c0_w[16 + q], sf, c0_b[16 + q]);
                    }
                    ap[16 + q][rr * 36 + exl] = v;
                }
            }
        }
    }
    __syncthreads();

    auto compute_px = [&](int ay, int ax, float* a1, float* a2) {
        const int ey = ay + 1, ex = ax + 1;   // ext coords
#pragma unroll
        for (int j = 0; j < 11; ++j) { a1[j] = c1_b[j]; a2[j] = c2_b[j]; }
#pragma unroll
        for (int c = 0; c < 22; ++c) {
            float dw = cs_b[c];
            float ctr = 0.0f;
#pragma unroll
            for (int t = 0; t < 9; ++t) {
                const float av = ap[c][(ey + t / 3 - 1) * 36 + (ex + t % 3 - 1)];
                dw = fmaf(cs_w[c * 9 + t], av, dw);
                if (t == 4) ctr = av;
            }
#pragma unroll
            for (int j = 0; j < 11; ++j) {
                a1[j] = fmaf(c1_w[j * 22 + c], ctr, a1[j]);
                a2[j] = fmaf(c2_w[j * 22 + c], dw, a2[j]);
            }
        }
    };

    // ---- phase 2a: ring jobs (84 halo pixels of the 10x34 agg region) ----
    if (tid < 84) {
        int ay, ax;
        if (tid < 34)      { ay = 0; ax = tid; }
        else if (tid < 68) { ay = 9; ax = tid - 34; }
        else { const int s = tid - 68; ay = 1 + (s >> 1); ax = (s & 1) ? 33 : 0; }
        const int gy = y0t + ay - 1, gx = x0 + ax - 1;
        float m0 = 0.0f, m1 = 0.0f;
        if (((unsigned)gy < (unsigned)HH) & ((unsigned)gx < (unsigned)WW)) {
            float a1h[11], a2h[11];
            compute_px(ay, ax, a1h, a2h);
            float s = 0.0f, mx = -INFINITY;
#pragma unroll
            for (int j = 0; j < 11; ++j) {
                s += a1h[j] + a2h[j];
                mx = fmaxf(mx, fmaxf(a1h[j], a2h[j]));
            }
            m0 = s * (1.0f / 22.0f);
            m1 = mx;
        }
        aggs[0][ay * 34 + ax] = m0;
        aggs[1][ay * 34 + ax] = m1;
    }

    // ---- phase 2b: center pixel, keep a1/a2 in registers ----
    const int ty = tid >> 5, tx = tid & 31;
    const int ay = ty + 1, ax = tx + 1;
    float a1[11], a2[11];
    compute_px(ay, ax, a1, a2);
    {
        float s = 0.0f, mx = -INFINITY;
#pragma unroll
        for (int j = 0; j < 11; ++j) {
            s += a1[j] + a2[j];
            mx = fmaxf(mx, fmaxf(a1[j], a2[j]));
        }
        aggs[0][ay * 34 + ax] = s * (1.0f / 22.0f);
        aggs[1][ay * 34 + ax] = mx;
    }
    __syncthreads();

    // ---- phase 3: sigmoid gate + cv + final dot with y ----
    float z0 = csq_b[0], z1 = csq_b[1];
#pragma unroll
    for (int t = 0; t < 9; ++t) {
        const int ai = (ay + t / 3 - 1) * 34 + (ax + t % 3 - 1);
        const float g0 = aggs[0][ai], g1 = aggs[1][ai];
        z0 = fmaf(csq_w[t], g0, fmaf(csq_w[9 + t], g1, z0));
        z1 = fmaf(csq_w[18 + t], g0, fmaf(csq_w[27 + t], g1, z1));
    }
    const float s0 = 1.0f / (1.0f + __expf(-z0));
    const float s1 = 1.0f / (1.0f + __expf(-z1));
    float v0 = cv_b[0], v1 = cv_b[1], v2 = cv_b[2];
#pragma unroll
    for (int j = 0; j < 11; ++j) {
        const float av = a1[j] * s0 + a2[j] * s1;
        v0 = fmaf(cv_w[j], av, v0);
        v1 = fmaf(cv_w[11 + j], av, v1);
        v2 = fmaf(cv_w[22 + j], av, v2);
    }
    const size_t p = (size_t)b * HW + (size_t)(y0t + ty) * WW + (x0 + tx);
    out[p] = y0s[p] * v0 + y1s[p] * v1 + y2s[p] * v2;
}

// ---------------------------------------------------------------------------
extern "C" void kernel_launch(void* const* d_in, const int* in_sizes, int n_in,
                              void* d_out, int out_size, void* d_ws, size_t ws_size,
                              hipStream_t stream)
{
    (void)in_sizes; (void)n_in; (void)out_size; (void)ws_size;
    const float* feat_init = (const float*)d_in[0];
    const float* guidance  = (const float*)d_in[1];
    const float* attn      = (const float*)d_in[2];
    const float* aff_w_w   = (const float*)d_in[4];
    const float* aff_w_b   = (const float*)d_in[5];
    const float* aff_o_w   = (const float*)d_in[6];
    const float* aff_o_b   = (const float*)d_in[7];
    const float* w3        = (const float*)d_in[8];
    const float* b3        = (const float*)d_in[9];
    const float* proj_w    = (const float*)d_in[10];
    const float* bn_g      = (const float*)d_in[11];
    const float* bn_b      = (const float*)d_in[12];
    const float* c0_w      = (const float*)d_in[13];
    const float* c0_b      = (const float*)d_in[14];
    const float* cs_w      = (const float*)d_in[15];
    const float* cs_b      = (const float*)d_in[16];
    const float* c1_w      = (const float*)d_in[17];
    const float* c1_b      = (const float*)d_in[18];
    const float* c2_w      = (const float*)d_in[19];
    const float* c2_b      = (const float*)d_in[20];
    const float* csq_w     = (const float*)d_in[21];
    const float* csq_b     = (const float*)d_in[22];
    const float* cv_w      = (const float*)d_in[23];
    const float* cv_b      = (const float*)d_in[24];

    float* ws = (float*)d_ws;
    float* slot[5];
    for (int i = 0; i < 5; ++i) slot[i] = ws + (size_t)i * NPIX;
    float* part  = ws + (size_t)5 * NPIX;
    float* stats = part + (size_t)9 * NPART;

    const dim3 blk(256);
    const dim3 gp(WW / 64, HH / 8, BATCH);

    // propagation chain; keep feats[3],[4],[5] in slots 2,3,4
    const int dst_ids[PROP] = {0, 1, 0, 2, 3, 4};
    const float* src = feat_init;
    for (int k = 0; k < PROP; ++k) {
        float* dst = slot[dst_ids[k]];
        prop_kernel<<<gp, blk, 0, stream>>>(
            src, guidance + (size_t)8 * k * HW,
            aff_w_w + (size_t)k * 648, aff_w_b + (size_t)k * 9,
            aff_o_w + (size_t)k * 1152, aff_o_b + (size_t)k * 16,
            w3, b3, dst);
        src = dst;
    }

    stats_part<<<dim3(NPART), blk, 0, stream>>>(slot[2], slot[3], slot[4], part);
    stats_final<<<dim3(1), blk, 0, stream>>>(part, proj_w, bn_g, bn_b, stats);

    head_kernel<<<dim3(HB_N), blk, 0, stream>>>(
        slot[2], slot[3], slot[4], attn, stats, proj_w,
        c0_w, c0_b, cs_w, cs_b, c1_w, c1_b, c2_w, c2_b,
        csq_w, csq_b, cv_w, cv_b, (float*)d_out);
}